// Round 9
// baseline (527.110 us; speedup 1.0000x reference)
//
#include <hip/hip_runtime.h>
#include <cfloat>

#define BATCH 4
#define P 8192
#define C 64
#define KNN 16
#define NPTS (BATCH * P)        // 32768
#define NEDGE (NPTS * KNN)      // 524288
#define EPSV 1e-5f
#define SLOPE 0.2f
#define NQ 2                    // column-range split per row-tile
#define QCOLS (P / NQ)          // 4096 cols per block
#define QCAP 16                 // lane-private LDS queue depth

typedef __attribute__((ext_vector_type(8))) short bf16x8;
typedef __attribute__((ext_vector_type(16))) float f32x16;

// ---------------- workspace layout (float element offsets) ----------------
// U      : [NPTS][C]   @ 0          (2097152)   written AFTER knn
// V      : [NPTS][C]   @ 2097152    (2097152)   written AFTER knn
// xfh/xfm/xfl bf16 frags alias U/V region (dead after knn)
// sq     : [NPTS]      @ 4194304    (32768)
// stats  : [128]       @ 4227072
// sshift : [128]       @ 4227200
// idx    : int[NEDGE]  @ 4227328    (524288)
// pv     : [NPTS][NQ][16] float @ 4751616 (1048576)
// pi     : [NPTS][NQ][16] int   @ 5800192 (1048576)
// total = 6848768 floats = 26.1 MB

__device__ __forceinline__ unsigned short f2bf(float f) {
    unsigned u = __float_as_uint(f);
    u += 0x7FFFu + ((u >> 16) & 1u);
    return (unsigned short)(u >> 16);
}
__device__ __forceinline__ float bf2f(unsigned short s) {
    return __uint_as_float(((unsigned)s) << 16);
}
// monotone float<->uint map: monof(a) < monof(b)  <=>  a < b (finite floats)
__device__ __forceinline__ unsigned monof(float f) {
    unsigned u = __float_as_uint(f);
    return u ^ ((unsigned)((int)u >> 31) | 0x80000000u);
}
__device__ __forceinline__ float invmonof(unsigned k) {
    unsigned u = (k & 0x80000000u) ? (k ^ 0x80000000u) : ~k;
    return __uint_as_float(u);
}

// ---------------------------------------------------------------------------
// K0: fragment-layout 3-way bf16 split of x + exact fp32 row norms.
// ---------------------------------------------------------------------------
__global__ void prep_frag(const float* __restrict__ x, uint4* __restrict__ xfh,
                          uint4* __restrict__ xfm, uint4* __restrict__ xfl,
                          float* __restrict__ sq) {
    __shared__ float part[32][9];
    int tid = threadIdx.x;
    int ptl = tid >> 3, j8 = tid & 7;
    int g = blockIdx.x;
    int p = g * 32 + ptl;
    const float4* xp = (const float4*)(x + (size_t)p * C + j8 * 8);
    float4 a = xp[0], b = xp[1];
    float v[8] = {a.x, a.y, a.z, a.w, b.x, b.y, b.z, b.w};
    unsigned short hs[8], ms[8], ls[8];
    float ssum = 0.f;
#pragma unroll
    for (int e = 0; e < 8; ++e) {
        float xv = v[e];
        ssum = fmaf(xv, xv, ssum);
        unsigned short h = f2bf(xv);
        float r1 = xv - bf2f(h);
        unsigned short m = f2bf(r1);
        float r2 = r1 - bf2f(m);
        unsigned short l = f2bf(r2);
        hs[e] = h; ms[e] = m; ls[e] = l;
    }
    int dst = (g * 4 + (j8 >> 1)) * 64 + ptl + 32 * (j8 & 1);
    uint4 ph, pm, pl;
    ph.x = (unsigned)hs[0] | ((unsigned)hs[1] << 16);
    ph.y = (unsigned)hs[2] | ((unsigned)hs[3] << 16);
    ph.z = (unsigned)hs[4] | ((unsigned)hs[5] << 16);
    ph.w = (unsigned)hs[6] | ((unsigned)hs[7] << 16);
    pm.x = (unsigned)ms[0] | ((unsigned)ms[1] << 16);
    pm.y = (unsigned)ms[2] | ((unsigned)ms[3] << 16);
    pm.z = (unsigned)ms[4] | ((unsigned)ms[5] << 16);
    pm.w = (unsigned)ms[6] | ((unsigned)ms[7] << 16);
    pl.x = (unsigned)ls[0] | ((unsigned)ls[1] << 16);
    pl.y = (unsigned)ls[2] | ((unsigned)ls[3] << 16);
    pl.z = (unsigned)ls[4] | ((unsigned)ls[5] << 16);
    pl.w = (unsigned)ls[6] | ((unsigned)ls[7] << 16);
    xfh[dst] = ph; xfm[dst] = pm; xfl[dst] = pl;
    part[ptl][j8] = ssum;
    __syncthreads();
    if (j8 == 0) {
        float s = 0.f;
#pragma unroll
        for (int k = 0; k < 8; ++k) s += part[ptl][k];
        sq[p] = s;
    }
}

// sorted-shift insert into ASC tv[16]/ti[16]: precomputed bools, descending
// in-place shift, all-static indexing, ~85 independent VALU. Strict '<':
// equal values keep the earlier-inserted (lower stream position).
#define SORTED_INS16(MV, IDV)                                                  \
    {                                                                          \
        float _m = (MV); int _id = (IDV);                                      \
        bool c0 = _m < tv[0], c1 = _m < tv[1], c2 = _m < tv[2],                \
             c3 = _m < tv[3], c4 = _m < tv[4], c5 = _m < tv[5],                \
             c6 = _m < tv[6], c7 = _m < tv[7], c8 = _m < tv[8],                \
             c9 = _m < tv[9], c10 = _m < tv[10], c11 = _m < tv[11],            \
             c12 = _m < tv[12], c13 = _m < tv[13], c14 = _m < tv[14],          \
             c15 = _m < tv[15];                                                \
        tv[15] = c15 ? (c14 ? tv[14] : _m) : tv[15];                           \
        ti[15] = c15 ? (c14 ? ti[14] : _id) : ti[15];                          \
        tv[14] = c14 ? (c13 ? tv[13] : _m) : tv[14];                           \
        ti[14] = c14 ? (c13 ? ti[13] : _id) : ti[14];                          \
        tv[13] = c13 ? (c12 ? tv[12] : _m) : tv[13];                           \
        ti[13] = c13 ? (c12 ? ti[12] : _id) : ti[13];                          \
        tv[12] = c12 ? (c11 ? tv[11] : _m) : tv[12];                           \
        ti[12] = c12 ? (c11 ? ti[11] : _id) : ti[12];                          \
        tv[11] = c11 ? (c10 ? tv[10] : _m) : tv[11];                           \
        ti[11] = c11 ? (c10 ? ti[10] : _id) : ti[11];                          \
        tv[10] = c10 ? (c9 ? tv[9] : _m) : tv[10];                             \
        ti[10] = c10 ? (c9 ? ti[9] : _id) : ti[10];                            \
        tv[9] = c9 ? (c8 ? tv[8] : _m) : tv[9];                                \
        ti[9] = c9 ? (c8 ? ti[8] : _id) : ti[9];                               \
        tv[8] = c8 ? (c7 ? tv[7] : _m) : tv[8];                                \
        ti[8] = c8 ? (c7 ? ti[7] : _id) : ti[8];                               \
        tv[7] = c7 ? (c6 ? tv[6] : _m) : tv[7];                                \
        ti[7] = c7 ? (c6 ? ti[6] : _id) : ti[7];                               \
        tv[6] = c6 ? (c5 ? tv[5] : _m) : tv[6];                                \
        ti[6] = c6 ? (c5 ? ti[5] : _id) : ti[6];                               \
        tv[5] = c5 ? (c4 ? tv[4] : _m) : tv[5];                                \
        ti[5] = c5 ? (c4 ? ti[4] : _id) : ti[5];                               \
        tv[4] = c4 ? (c3 ? tv[3] : _m) : tv[4];                                \
        ti[4] = c4 ? (c3 ? ti[3] : _id) : ti[4];                               \
        tv[3] = c3 ? (c2 ? tv[2] : _m) : tv[3];                                \
        ti[3] = c3 ? (c2 ? ti[2] : _id) : ti[3];                               \
        tv[2] = c2 ? (c1 ? tv[1] : _m) : tv[2];                                \
        ti[2] = c2 ? (c1 ? ti[1] : _id) : ti[2];                               \
        tv[1] = c1 ? (c0 ? tv[0] : _m) : tv[1];                                \
        ti[1] = c1 ? (c0 ? ti[0] : _id) : ti[1];                               \
        tv[0] = c0 ? _m : tv[0];                                               \
        ti[0] = c0 ? _id : ti[0];                                              \
    }

// wave-uniform drain, dynamically bounded by the wave-max queue fill (MXV).
// Runtime (non-unrolled) loop; invalid slots insert FLT_MAX (no-op under
// strict '<'). FIFO order = push order = column order -> ties preserved.
#define DRAIN_QN(MXV)                                                          \
    {                                                                          \
        _Pragma("nounroll")                                                    \
        for (int j = 0; j < (MXV); ++j) {                                      \
            unsigned long long kq = q[j * 256 + tid];                          \
            bool valid = (j < qn);                                             \
            float dv = valid ? __uint_as_float((unsigned)(kq >> 32)) : FLT_MAX;\
            int di = (int)(unsigned)(kq & 0xFFFFFFFFu);                        \
            SORTED_INS16(dv, di)                                               \
        }                                                                      \
        qn = 0;                                                                \
    }

// 64-lane max reduce (butterfly)
#define WAVE_MAX(DST, SRC)                                                     \
    {                                                                          \
        int _m = (SRC);                                                        \
        _m = max(_m, __shfl_xor(_m, 1));                                       \
        _m = max(_m, __shfl_xor(_m, 2));                                       \
        _m = max(_m, __shfl_xor(_m, 4));                                       \
        _m = max(_m, __shfl_xor(_m, 8));                                       \
        _m = max(_m, __shfl_xor(_m, 16));                                      \
        _m = max(_m, __shfl_xor(_m, 32));                                      \
        (DST) = _m;                                                            \
    }

// ---------------------------------------------------------------------------
// K1: KNN r14 — transposed MFMA + register top-16 + batched LDS-queue drains.
//
// r13 post-mortem: 403us, ~58K VALU instr/wave (model said 25K). Residuals:
// (1) fixed-8 drains at ~50% slot fill, fired off the busiest lane (~30-40
// events); (2) per-site __any checks (16/chunk); (3) VGPR=64 squeeze hint.
//
// r14 (skeleton unchanged from r13):
//  * QCAP 16 (queue [16][256] u64 = 32KB, still aliased under the 33.3KB
//    fink buffer -> LDS 33.3KB, 4 blocks/CU, grid = one full residency).
//  * drain checks TWICE per chunk (chunk start + before site 8), trigger
//    __any(qn >= 8). Max 8 pushes between checks -> qn <= 15 < QCAP, no
//    overflow; drains batch >= 8 items on the trigger lane (~10 events).
//  * drain iterations bounded by wave_max(qn) (6-step shfl_xor) instead of
//    fixed capacity -> no-op slots mostly eliminated.
// Expected ~28K VALU instr/wave (vs r13 ~58K).
// ---------------------------------------------------------------------------
__global__ __launch_bounds__(256, 4) void knn_kernel(const uint4* __restrict__ xfh,
                                                     const uint4* __restrict__ xfm,
                                                     const uint4* __restrict__ xfl,
                                                     const float* __restrict__ sq,
                                                     float* __restrict__ pv,
                                                     int* __restrict__ pi) {
    __shared__ unsigned long long smem[64 * 65];   // 33280 B
    unsigned long long* q = smem;                  // queue alias: [QCAP][256]
    unsigned long long (*fink)[65] = (unsigned long long (*)[65])smem;

    int tid = threadIdx.x;
    int b = blockIdx.x & 3;              // batch -> XCDs {b, b+4}: frags L2-resident
    int t = blockIdx.x >> 2;
    int tile = t & 127;
    int half = t >> 7;
    int bglob = b * P;
    int r0 = tile * 64;
    int w = tid >> 6, lane = tid & 63;
    int wr = w & 1, wc = w >> 1;
    int hi = lane >> 5;                  // col-offset selector (+4)
    int rloc = lane & 31;                // row owned by this lane (within wave tile)

    // persistent ROW fragments ("B" operand): rows r0 + 32*wr .. +32
    int gA = ((bglob + r0) >> 5) + wr;
    bf16x8 Rh[4], Rm[4], Rl[4];
#pragma unroll
    for (int kk = 0; kk < 4; ++kk) {
        Rh[kk] = __builtin_bit_cast(bf16x8, xfh[(gA * 4 + kk) * 64 + lane]);
        Rm[kk] = __builtin_bit_cast(bf16x8, xfm[(gA * 4 + kk) * 64 + lane]);
        Rl[kk] = __builtin_bit_cast(bf16x8, xfl[(gA * 4 + kk) * 64 + lane]);
    }

    // per-lane sorted top-16 (ASC) + LDS queue count
    float tv[16];
    int   ti[16];
#pragma unroll
    for (int j = 0; j < 16; ++j) { tv[j] = FLT_MAX; ti[j] = 0; }
    int qn = 0;

    int cw0 = half * QCOLS + wc * 2048;  // this wave's 2048-col range (64 chunks x 32)

    for (int chunk = 0; chunk < 64; ++chunk) {
        int c0 = cw0 + chunk * 32;
        int gB = (bglob + c0) >> 5;
        const uint4* ch = &xfh[(gB * 4) * 64 + lane];
        const uint4* cm = &xfm[(gB * 4) * 64 + lane];
        const uint4* cl = &xfl[(gB * 4) * 64 + lane];

        f32x16 acc0, acc1;
#pragma unroll
        for (int i = 0; i < 16; ++i) { acc0[i] = 0.f; acc1[i] = 0.f; }
#pragma unroll
        for (int kk = 0; kk < 4; ++kk) {
            bf16x8 Ch = __builtin_bit_cast(bf16x8, ch[kk * 64]);
            bf16x8 Cm = __builtin_bit_cast(bf16x8, cm[kk * 64]);
            bf16x8 Cl = __builtin_bit_cast(bf16x8, cl[kk * 64]);
            acc0 = __builtin_amdgcn_mfma_f32_32x32x16_bf16(Ch, Rh[kk], acc0, 0, 0, 0);
            acc1 = __builtin_amdgcn_mfma_f32_32x32x16_bf16(Ch, Rm[kk], acc1, 0, 0, 0);
            acc0 = __builtin_amdgcn_mfma_f32_32x32x16_bf16(Cm, Rh[kk], acc0, 0, 0, 0);
            acc1 = __builtin_amdgcn_mfma_f32_32x32x16_bf16(Cm, Rm[kk], acc1, 0, 0, 0);
            acc0 = __builtin_amdgcn_mfma_f32_32x32x16_bf16(Ch, Rl[kk], acc0, 0, 0, 0);
            acc1 = __builtin_amdgcn_mfma_f32_32x32x16_bf16(Cl, Rh[kk], acc1, 0, 0, 0);
        }

        // col norms for this lane's 16 cols (uniform per half-wave, L1-hit)
        int cb = c0 + 4 * hi;
        float4 sqA[4];
#pragma unroll
        for (int g4 = 0; g4 < 4; ++g4)
            sqA[g4] = *(const float4*)(&sq[bglob + cb + g4 * 8]);
        int bgc = bglob + cb;            // GLOBAL col id base

        // site loop: s' = sq_col - 2 x.y (sq_row dropped: rank-invariant).
        // drain checks at reg==0 and reg==8 only (max 8 pushes between
        // checks; trigger qn>=8 -> qn <= 15 < QCAP always).
#pragma unroll
        for (int reg = 0; reg < 16; ++reg) {
            if (reg == 0 || reg == 8) {
                if (__any(qn >= 8)) {
                    int mx; WAVE_MAX(mx, qn)
                    DRAIN_QN(mx)
                }
            }
            float s = fmaf(-2.f, acc0[reg] + acc1[reg],
                           ((const float*)&sqA[reg >> 2])[reg & 3]);
            bool pass = s < tv[15];
            if (pass) {
                int cid = bgc + (reg & 3) + 8 * (reg >> 2);
                unsigned long long kk =
                    ((unsigned long long)__float_as_uint(s) << 32) | (unsigned)cid;
                q[qn * 256 + tid] = kk;
                qn += 1;
            }
        }
    }

    // final drain (wave-uniform; qn <= 15)
    {
        int mx; WAVE_MAX(mx, qn)
        DRAIN_QN(mx)
    }

    __syncthreads();   // queue region dead everywhere -> safe to alias as fink

    // ---- block-end merge: 4 lists/row -> 1 list/row via u64 keys ----
    {
        int rowl = 32 * wr + rloc;
        int li = wc * 2 + hi;            // list index 0..3
#pragma unroll
        for (int j = 0; j < 16; ++j)
            fink[rowl][li * 16 + j] =
                ((unsigned long long)monof(tv[j]) << 32) | (unsigned)ti[j];
    }
    __syncthreads();
    if (tid < 128) {                     // stage 1: merge list pairs (0,1) and (2,3)
        int row = tid & 63, pr = tid >> 6;
        int base = pr * 32;
        unsigned long long tk[16];
#pragma unroll
        for (int j = 0; j < 16; ++j) tk[j] = fink[row][base + j];
        unsigned long long worstk = tk[0];
#pragma unroll
        for (int j = 1; j < 16; ++j) worstk = (tk[j] > worstk) ? tk[j] : worstk;
        for (int e = 0; e < 16; ++e) {
            unsigned long long k = fink[row][base + 16 + e];
            if (k < worstk) {
                unsigned long long mx = tk[0]; int pos = 0;
#pragma unroll
                for (int j = 1; j < 16; ++j) {
                    bool g = tk[j] > mx; mx = g ? tk[j] : mx; pos = g ? j : pos;
                }
#pragma unroll
                for (int j = 0; j < 16; ++j)
                    if (j == pos) tk[j] = k;
                unsigned long long nw = tk[0];
#pragma unroll
                for (int j = 1; j < 16; ++j) nw = (tk[j] > nw) ? tk[j] : nw;
                worstk = nw;
            }
        }
#pragma unroll
        for (int j = 0; j < 16; ++j) fink[row][base + j] = tk[j];
    }
    __syncthreads();
    if (tid < 64) {                      // stage 2: merge (0+1) with (2+3), write out
        int row = tid;
        unsigned long long tk[16];
#pragma unroll
        for (int j = 0; j < 16; ++j) tk[j] = fink[row][j];
        unsigned long long worstk = tk[0];
#pragma unroll
        for (int j = 1; j < 16; ++j) worstk = (tk[j] > worstk) ? tk[j] : worstk;
        for (int e = 0; e < 16; ++e) {
            unsigned long long k = fink[row][32 + e];
            if (k < worstk) {
                unsigned long long mx = tk[0]; int pos = 0;
#pragma unroll
                for (int j = 1; j < 16; ++j) {
                    bool g = tk[j] > mx; mx = g ? tk[j] : mx; pos = g ? j : pos;
                }
#pragma unroll
                for (int j = 0; j < 16; ++j)
                    if (j == pos) tk[j] = k;
                unsigned long long nw = tk[0];
#pragma unroll
                for (int j = 1; j < 16; ++j) nw = (tk[j] > nw) ? tk[j] : nw;
                worstk = nw;
            }
        }
        size_t o = (((size_t)(bglob + r0 + row)) * NQ + half) * KNN;
#pragma unroll
        for (int j = 0; j < 16; ++j) {
            pv[o + j] = invmonof((unsigned)(tk[j] >> 32));
            pi[o + j] = (int)(unsigned)(tk[j] & 0xFFFFFFFFu);
        }
    }
}

// ---------------------------------------------------------------------------
// K1b: merge NQ=2 partial top-16 lists per row -> final idx (u64-key exact).
// ---------------------------------------------------------------------------
__global__ void merge_kernel(const float* __restrict__ pv, const int* __restrict__ pi,
                             int* __restrict__ idx_out) {
    __shared__ unsigned long long mk[128 * 33];
    int tid = threadIdx.x;
    int lr = tid & 127, q = tid >> 7;
    int row = blockIdx.x * 128 + lr;
    size_t o = ((size_t)row * NQ + q) * KNN;
#pragma unroll
    for (int j = 0; j < 16; ++j) {
        mk[lr * 33 + q * 16 + j] =
            ((unsigned long long)monof(pv[o + j]) << 32) | (unsigned)pi[o + j];
    }
    __syncthreads();
    if (tid < 128) {
        unsigned long long tk[16];
#pragma unroll
        for (int j = 0; j < 16; ++j) tk[j] = mk[tid * 33 + j];
        unsigned long long worstk = tk[0];
#pragma unroll
        for (int j = 1; j < 16; ++j) worstk = (tk[j] > worstk) ? tk[j] : worstk;
        for (int e = 16; e < 32; ++e) {
            unsigned long long k = mk[tid * 33 + e];
            if (k < worstk) {
                unsigned long long mx = tk[0]; int pos = 0;
#pragma unroll
                for (int j = 1; j < 16; ++j) {
                    bool g = tk[j] > mx; mx = g ? tk[j] : mx; pos = g ? j : pos;
                }
#pragma unroll
                for (int j = 0; j < 16; ++j)
                    if (j == pos) tk[j] = k;
                unsigned long long nw = tk[0];
#pragma unroll
                for (int j = 1; j < 16; ++j) nw = (tk[j] > nw) ? tk[j] : nw;
                worstk = nw;
            }
        }
        size_t oo = (size_t)tid * KNN + (size_t)blockIdx.x * 128 * KNN;
#pragma unroll
        for (int j = 0; j < 16; ++j)
            idx_out[oo + j] = (int)(unsigned)(tk[j] & 0xFFFFFFFFu);
    }
}

// ---------------------------------------------------------------------------
// K2: U = x @ (W1 - W2), V = x @ W2
// ---------------------------------------------------------------------------
__global__ void prep_UV(const float* __restrict__ x, const float* __restrict__ W,
                        float* __restrict__ U, float* __restrict__ V) {
    __shared__ float Ws[128][64];
    __shared__ float xs[4][64];
    int tid = threadIdx.x;
    for (int i = tid; i < 128 * 64; i += 256) ((float*)Ws)[i] = W[i];
    int p0 = blockIdx.x * 4;
    int r = tid >> 6, c = tid & 63;
    xs[r][c] = x[(size_t)(p0 + r) * C + c];
    __syncthreads();
    float u = 0.f, v = 0.f;
#pragma unroll
    for (int k = 0; k < 64; ++k) {
        float xv = xs[r][k];
        float w1 = Ws[k][c];
        float w2 = Ws[64 + k][c];
        u = fmaf(xv, w1 - w2, u);
        v = fmaf(xv, w2, v);
    }
    size_t o = (size_t)(p0 + r) * C + c;
    U[o] = u;
    V[o] = v;
}

// ---------------------------------------------------------------------------
// K3: BN stats
// ---------------------------------------------------------------------------
__global__ void stats_kernel(const float* __restrict__ U, const float* __restrict__ V,
                             const float* __restrict__ bias, const int* __restrict__ idx,
                             float* __restrict__ stats) {
    int tid = threadIdx.x;
    int c = tid & 63, kk = tid >> 6;
    int p0 = blockIdx.x * 32;
    float bc = bias[c];
    float sum = 0.f, sumsq = 0.f;
    for (int pp = 0; pp < 32; ++pp) {
        int p = p0 + pp;
        float u = U[(size_t)p * C + c] + bc;
#pragma unroll
        for (int k4 = 0; k4 < 4; ++k4) {
            int j = idx[(size_t)p * KNN + kk * 4 + k4];
            float h = u + V[(size_t)j * C + c];
            sum += h;
            sumsq = fmaf(h, h, sumsq);
        }
    }
    __shared__ float red[2][4][64];
    red[0][kk][c] = sum;
    red[1][kk][c] = sumsq;
    __syncthreads();
    if (tid < 64) {
        float s = red[0][0][tid] + red[0][1][tid] + red[0][2][tid] + red[0][3][tid];
        atomicAdd(&stats[tid], s);
    } else if (tid < 128) {
        int cc = tid - 64;
        float s = red[1][0][cc] + red[1][1][cc] + red[1][2][cc] + red[1][3][cc];
        atomicAdd(&stats[64 + cc], s);
    }
}

__global__ void finalize_kernel(const float* __restrict__ stats,
                                const float* __restrict__ gamma,
                                const float* __restrict__ beta,
                                float* __restrict__ sshift) {
    int c = threadIdx.x;
    const float N = (float)NEDGE;
    float mean = stats[c] / N;
    float var = stats[64 + c] / N - mean * mean;
    float s = gamma[c] * rsqrtf(var + EPSV);
    sshift[c] = s;
    sshift[64 + c] = beta[c] - mean * s;
}

// ---------------------------------------------------------------------------
// K5: out = lrelu(s*(U+b + max/min_k V[idx]) + t)  (monotone fusion of max_k)
// ---------------------------------------------------------------------------
__global__ void out_kernel(const float* __restrict__ U, const float* __restrict__ V,
                           const float* __restrict__ bias, const int* __restrict__ idx,
                           const float* __restrict__ sshift, float* __restrict__ out) {
    int tid = threadIdx.x;
    int c = tid & 63, g = tid >> 6;
    int p0 = blockIdx.x * 16;
    float s = sshift[c], t = sshift[64 + c];
    float bc = bias[c];
    for (int pp = g; pp < 16; pp += 4) {
        int p = p0 + pp;
        float mx = -FLT_MAX, mn = FLT_MAX;
#pragma unroll
        for (int k = 0; k < KNN; ++k) {
            int j = idx[(size_t)p * KNN + k];
            float v = V[(size_t)j * C + c];
            mx = fmaxf(mx, v);
            mn = fminf(mn, v);
        }
        float hsel = (s >= 0.f) ? mx : mn;
        float hn = fmaf(s, U[(size_t)p * C + c] + bc + hsel, t);
        out[(size_t)p * C + c] = (hn >= 0.f) ? hn : SLOPE * hn;
    }
}

// ---------------------------------------------------------------------------
extern "C" void kernel_launch(void* const* d_in, const int* in_sizes, int n_in,
                              void* d_out, int out_size, void* d_ws, size_t ws_size,
                              hipStream_t stream) {
    const float* x     = (const float*)d_in[0];
    const float* W     = (const float*)d_in[2];
    const float* bias  = (const float*)d_in[3];
    const float* gamma = (const float*)d_in[4];
    const float* beta  = (const float*)d_in[5];
    float* out = (float*)d_out;

    float* wsf    = (float*)d_ws;
    float* U      = wsf;
    float* V      = wsf + 2097152;
    uint4* xfh    = (uint4*)wsf;                   // aliases U/V, dead after knn
    uint4* xfm    = (uint4*)(wsf + 1048576);
    uint4* xfl    = (uint4*)(wsf + 2097152);
    float* sq     = wsf + 4194304;
    float* stats  = wsf + 4227072;
    float* sshift = wsf + 4227200;
    int*   idx    = (int*)(wsf + 4227328);
    float* pv     = wsf + 4751616;
    int*   pi     = (int*)(wsf + 5800192);

    hipLaunchKernelGGL(prep_frag, dim3(NPTS / 32), dim3(256), 0, stream, x, xfh, xfm, xfl, sq);
    hipLaunchKernelGGL(knn_kernel, dim3(BATCH * (P / 64) * NQ), dim3(256), 0, stream,
                       (const uint4*)xfh, (const uint4*)xfm, (const uint4*)xfl, sq, pv, pi);
    hipLaunchKernelGGL(merge_kernel, dim3(NPTS / 128), dim3(256), 0, stream, pv, pi, idx);
    hipLaunchKernelGGL(prep_UV, dim3(NPTS / 4), dim3(256), 0, stream, x, W, U, V);
    hipMemsetAsync(stats, 0, 128 * sizeof(float), stream);
    hipLaunchKernelGGL(stats_kernel, dim3(NPTS / 32), dim3(256), 0, stream, U, V, bias, idx, stats);
    hipLaunchKernelGGL(finalize_kernel, dim3(1), dim3(64), 0, stream, stats, gamma, beta, sshift);
    hipLaunchKernelGGL(out_kernel, dim3(NPTS / 16), dim3(256), 0, stream, U, V, bias, idx, sshift, out);
}

// Round 10
// 525.535 us; speedup vs baseline: 1.0030x; 1.0030x over previous
//
#include <hip/hip_runtime.h>
#include <cfloat>

#define BATCH 4
#define P 8192
#define C 64
#define KNN 16
#define NPTS (BATCH * P)        // 32768
#define NEDGE (NPTS * KNN)      // 524288
#define EPSV 1e-5f
#define SLOPE 0.2f
#define NQ 2                    // column-range split per row-tile
#define QCOLS (P / NQ)          // 4096 cols per block
#define QCAP 16                 // lane-private LDS queue depth

typedef __attribute__((ext_vector_type(8))) short bf16x8;
typedef __attribute__((ext_vector_type(16))) float f32x16;

// ---------------- workspace layout (float element offsets) ----------------
// U      : [NPTS][C]   @ 0          (2097152)   written AFTER knn
// V      : [NPTS][C]   @ 2097152    (2097152)   written AFTER knn
// xfh/xfm/xfl bf16 frags alias U/V region (dead after knn)
// sq     : [NPTS]      @ 4194304    (32768)
// stats  : [128]       @ 4227072
// sshift : [128]       @ 4227200
// idx    : int[NEDGE]  @ 4227328    (524288)
// pv     : [NPTS][NQ][16] float @ 4751616 (1048576)
// pi     : [NPTS][NQ][16] int   @ 5800192 (1048576)
// total = 6848768 floats = 26.1 MB

__device__ __forceinline__ unsigned short f2bf(float f) {
    unsigned u = __float_as_uint(f);
    u += 0x7FFFu + ((u >> 16) & 1u);
    return (unsigned short)(u >> 16);
}
__device__ __forceinline__ float bf2f(unsigned short s) {
    return __uint_as_float(((unsigned)s) << 16);
}
// monotone float<->uint map: monof(a) < monof(b)  <=>  a < b (finite floats)
__device__ __forceinline__ unsigned monof(float f) {
    unsigned u = __float_as_uint(f);
    return u ^ ((unsigned)((int)u >> 31) | 0x80000000u);
}
__device__ __forceinline__ float invmonof(unsigned k) {
    unsigned u = (k & 0x80000000u) ? (k ^ 0x80000000u) : ~k;
    return __uint_as_float(u);
}

// ---------------------------------------------------------------------------
// K0: fragment-layout 3-way bf16 split of x + exact fp32 row norms.
// ---------------------------------------------------------------------------
__global__ void prep_frag(const float* __restrict__ x, uint4* __restrict__ xfh,
                          uint4* __restrict__ xfm, uint4* __restrict__ xfl,
                          float* __restrict__ sq) {
    __shared__ float part[32][9];
    int tid = threadIdx.x;
    int ptl = tid >> 3, j8 = tid & 7;
    int g = blockIdx.x;
    int p = g * 32 + ptl;
    const float4* xp = (const float4*)(x + (size_t)p * C + j8 * 8);
    float4 a = xp[0], b = xp[1];
    float v[8] = {a.x, a.y, a.z, a.w, b.x, b.y, b.z, b.w};
    unsigned short hs[8], ms[8], ls[8];
    float ssum = 0.f;
#pragma unroll
    for (int e = 0; e < 8; ++e) {
        float xv = v[e];
        ssum = fmaf(xv, xv, ssum);
        unsigned short h = f2bf(xv);
        float r1 = xv - bf2f(h);
        unsigned short m = f2bf(r1);
        float r2 = r1 - bf2f(m);
        unsigned short l = f2bf(r2);
        hs[e] = h; ms[e] = m; ls[e] = l;
    }
    int dst = (g * 4 + (j8 >> 1)) * 64 + ptl + 32 * (j8 & 1);
    uint4 ph, pm, pl;
    ph.x = (unsigned)hs[0] | ((unsigned)hs[1] << 16);
    ph.y = (unsigned)hs[2] | ((unsigned)hs[3] << 16);
    ph.z = (unsigned)hs[4] | ((unsigned)hs[5] << 16);
    ph.w = (unsigned)hs[6] | ((unsigned)hs[7] << 16);
    pm.x = (unsigned)ms[0] | ((unsigned)ms[1] << 16);
    pm.y = (unsigned)ms[2] | ((unsigned)ms[3] << 16);
    pm.z = (unsigned)ms[4] | ((unsigned)ms[5] << 16);
    pm.w = (unsigned)ms[6] | ((unsigned)ms[7] << 16);
    pl.x = (unsigned)ls[0] | ((unsigned)ls[1] << 16);
    pl.y = (unsigned)ls[2] | ((unsigned)ls[3] << 16);
    pl.z = (unsigned)ls[4] | ((unsigned)ls[5] << 16);
    pl.w = (unsigned)ls[6] | ((unsigned)ls[7] << 16);
    xfh[dst] = ph; xfm[dst] = pm; xfl[dst] = pl;
    part[ptl][j8] = ssum;
    __syncthreads();
    if (j8 == 0) {
        float s = 0.f;
#pragma unroll
        for (int k = 0; k < 8; ++k) s += part[ptl][k];
        sq[p] = s;
    }
}

// sorted-shift insert into ASC tv[16]/ti[16]: precomputed bools, descending
// in-place shift, all-static indexing, ~85 independent VALU. Strict '<':
// equal values keep the earlier-inserted (lower stream position).
#define SORTED_INS16(MV, IDV)                                                  \
    {                                                                          \
        float _m = (MV); int _id = (IDV);                                      \
        bool c0 = _m < tv[0], c1 = _m < tv[1], c2 = _m < tv[2],                \
             c3 = _m < tv[3], c4 = _m < tv[4], c5 = _m < tv[5],                \
             c6 = _m < tv[6], c7 = _m < tv[7], c8 = _m < tv[8],                \
             c9 = _m < tv[9], c10 = _m < tv[10], c11 = _m < tv[11],            \
             c12 = _m < tv[12], c13 = _m < tv[13], c14 = _m < tv[14],          \
             c15 = _m < tv[15];                                                \
        tv[15] = c15 ? (c14 ? tv[14] : _m) : tv[15];                           \
        ti[15] = c15 ? (c14 ? ti[14] : _id) : ti[15];                          \
        tv[14] = c14 ? (c13 ? tv[13] : _m) : tv[14];                           \
        ti[14] = c14 ? (c13 ? ti[13] : _id) : ti[14];                          \
        tv[13] = c13 ? (c12 ? tv[12] : _m) : tv[13];                           \
        ti[13] = c13 ? (c12 ? ti[12] : _id) : ti[13];                          \
        tv[12] = c12 ? (c11 ? tv[11] : _m) : tv[12];                           \
        ti[12] = c12 ? (c11 ? ti[11] : _id) : ti[12];                          \
        tv[11] = c11 ? (c10 ? tv[10] : _m) : tv[11];                           \
        ti[11] = c11 ? (c10 ? ti[10] : _id) : ti[11];                          \
        tv[10] = c10 ? (c9 ? tv[9] : _m) : tv[10];                             \
        ti[10] = c10 ? (c9 ? ti[9] : _id) : ti[10];                            \
        tv[9] = c9 ? (c8 ? tv[8] : _m) : tv[9];                                \
        ti[9] = c9 ? (c8 ? ti[8] : _id) : ti[9];                               \
        tv[8] = c8 ? (c7 ? tv[7] : _m) : tv[8];                                \
        ti[8] = c8 ? (c7 ? ti[7] : _id) : ti[8];                               \
        tv[7] = c7 ? (c6 ? tv[6] : _m) : tv[7];                                \
        ti[7] = c7 ? (c6 ? ti[6] : _id) : ti[7];                               \
        tv[6] = c6 ? (c5 ? tv[5] : _m) : tv[6];                                \
        ti[6] = c6 ? (c5 ? ti[5] : _id) : ti[6];                               \
        tv[5] = c5 ? (c4 ? tv[4] : _m) : tv[5];                                \
        ti[5] = c5 ? (c4 ? ti[4] : _id) : ti[5];                               \
        tv[4] = c4 ? (c3 ? tv[3] : _m) : tv[4];                                \
        ti[4] = c4 ? (c3 ? ti[3] : _id) : ti[4];                               \
        tv[3] = c3 ? (c2 ? tv[2] : _m) : tv[3];                                \
        ti[3] = c3 ? (c2 ? ti[2] : _id) : ti[3];                               \
        tv[2] = c2 ? (c1 ? tv[1] : _m) : tv[2];                                \
        ti[2] = c2 ? (c1 ? ti[1] : _id) : ti[2];                               \
        tv[1] = c1 ? (c0 ? tv[0] : _m) : tv[1];                                \
        ti[1] = c1 ? (c0 ? ti[0] : _id) : ti[1];                               \
        tv[0] = c0 ? _m : tv[0];                                               \
        ti[0] = c0 ? _id : ti[0];                                              \
    }

// wave-uniform drain, dynamically bounded by the wave-max queue fill (MXV).
// Runtime (non-unrolled) loop; invalid slots insert FLT_MAX (no-op under
// strict '<'). FIFO order = push order = column order -> ties preserved.
#define DRAIN_QN(MXV)                                                          \
    {                                                                          \
        _Pragma("nounroll")                                                    \
        for (int j = 0; j < (MXV); ++j) {                                      \
            unsigned long long kq = q[j * 256 + tid];                          \
            bool valid = (j < qn);                                             \
            float dv = valid ? __uint_as_float((unsigned)(kq >> 32)) : FLT_MAX;\
            int di = (int)(unsigned)(kq & 0xFFFFFFFFu);                        \
            SORTED_INS16(dv, di)                                               \
        }                                                                      \
        qn = 0;                                                                \
    }

// 64-lane max reduce (butterfly)
#define WAVE_MAX(DST, SRC)                                                     \
    {                                                                          \
        int _m = (SRC);                                                        \
        _m = max(_m, __shfl_xor(_m, 1));                                       \
        _m = max(_m, __shfl_xor(_m, 2));                                       \
        _m = max(_m, __shfl_xor(_m, 4));                                       \
        _m = max(_m, __shfl_xor(_m, 8));                                       \
        _m = max(_m, __shfl_xor(_m, 16));                                      \
        _m = max(_m, __shfl_xor(_m, 32));                                      \
        (DST) = _m;                                                            \
    }

// ---------------------------------------------------------------------------
// K1: KNN r15 — r14 structure at __launch_bounds__(256, 3).
//
// r14 post-mortem: 418us, same ~57K instr/wave as r13 — drain batching was
// not the residual. VGPR_Count stuck at 64 under (256,4): live state needs
// ~95 arch VGPRs (48 R-frags + 32 tv/ti + misc), so tv/ti were allocated in
// AGPRs -> every SORTED_INS16 pays ~64-128 v_accvgpr_read/write on top of
// its 85 ops. ~300 inserts x ~180 effective = 54K ~= the measured 57K.
//
// r15 (only change): __launch_bounds__(256, 3) -> ~170 unified regs. All of
// tv/ti register-resident; inserts at true cost. Price: 3 blocks/CU (LDS
// wasn't the limiter) -> grid 1024 runs 768 + 256-block tail (~+20% tail on
// a much shorter kernel). Smoking-gun check: VGPR_Count must jump to ~100+.
// ---------------------------------------------------------------------------
__global__ __launch_bounds__(256, 3) void knn_kernel(const uint4* __restrict__ xfh,
                                                     const uint4* __restrict__ xfm,
                                                     const uint4* __restrict__ xfl,
                                                     const float* __restrict__ sq,
                                                     float* __restrict__ pv,
                                                     int* __restrict__ pi) {
    __shared__ unsigned long long smem[64 * 65];   // 33280 B
    unsigned long long* q = smem;                  // queue alias: [QCAP][256]
    unsigned long long (*fink)[65] = (unsigned long long (*)[65])smem;

    int tid = threadIdx.x;
    int b = blockIdx.x & 3;              // batch -> XCDs {b, b+4}: frags L2-resident
    int t = blockIdx.x >> 2;
    int tile = t & 127;
    int half = t >> 7;
    int bglob = b * P;
    int r0 = tile * 64;
    int w = tid >> 6, lane = tid & 63;
    int wr = w & 1, wc = w >> 1;
    int hi = lane >> 5;                  // col-offset selector (+4)
    int rloc = lane & 31;                // row owned by this lane (within wave tile)

    // persistent ROW fragments ("B" operand): rows r0 + 32*wr .. +32
    int gA = ((bglob + r0) >> 5) + wr;
    bf16x8 Rh[4], Rm[4], Rl[4];
#pragma unroll
    for (int kk = 0; kk < 4; ++kk) {
        Rh[kk] = __builtin_bit_cast(bf16x8, xfh[(gA * 4 + kk) * 64 + lane]);
        Rm[kk] = __builtin_bit_cast(bf16x8, xfm[(gA * 4 + kk) * 64 + lane]);
        Rl[kk] = __builtin_bit_cast(bf16x8, xfl[(gA * 4 + kk) * 64 + lane]);
    }

    // per-lane sorted top-16 (ASC) + LDS queue count
    float tv[16];
    int   ti[16];
#pragma unroll
    for (int j = 0; j < 16; ++j) { tv[j] = FLT_MAX; ti[j] = 0; }
    int qn = 0;

    int cw0 = half * QCOLS + wc * 2048;  // this wave's 2048-col range (64 chunks x 32)

    for (int chunk = 0; chunk < 64; ++chunk) {
        int c0 = cw0 + chunk * 32;
        int gB = (bglob + c0) >> 5;
        const uint4* ch = &xfh[(gB * 4) * 64 + lane];
        const uint4* cm = &xfm[(gB * 4) * 64 + lane];
        const uint4* cl = &xfl[(gB * 4) * 64 + lane];

        f32x16 acc0, acc1;
#pragma unroll
        for (int i = 0; i < 16; ++i) { acc0[i] = 0.f; acc1[i] = 0.f; }
#pragma unroll
        for (int kk = 0; kk < 4; ++kk) {
            bf16x8 Ch = __builtin_bit_cast(bf16x8, ch[kk * 64]);
            bf16x8 Cm = __builtin_bit_cast(bf16x8, cm[kk * 64]);
            bf16x8 Cl = __builtin_bit_cast(bf16x8, cl[kk * 64]);
            acc0 = __builtin_amdgcn_mfma_f32_32x32x16_bf16(Ch, Rh[kk], acc0, 0, 0, 0);
            acc1 = __builtin_amdgcn_mfma_f32_32x32x16_bf16(Ch, Rm[kk], acc1, 0, 0, 0);
            acc0 = __builtin_amdgcn_mfma_f32_32x32x16_bf16(Cm, Rh[kk], acc0, 0, 0, 0);
            acc1 = __builtin_amdgcn_mfma_f32_32x32x16_bf16(Cm, Rm[kk], acc1, 0, 0, 0);
            acc0 = __builtin_amdgcn_mfma_f32_32x32x16_bf16(Ch, Rl[kk], acc0, 0, 0, 0);
            acc1 = __builtin_amdgcn_mfma_f32_32x32x16_bf16(Cl, Rh[kk], acc1, 0, 0, 0);
        }

        // col norms for this lane's 16 cols (uniform per half-wave, L1-hit)
        int cb = c0 + 4 * hi;
        float4 sqA[4];
#pragma unroll
        for (int g4 = 0; g4 < 4; ++g4)
            sqA[g4] = *(const float4*)(&sq[bglob + cb + g4 * 8]);
        int bgc = bglob + cb;            // GLOBAL col id base

        // site loop: s' = sq_col - 2 x.y (sq_row dropped: rank-invariant).
        // drain checks at reg==0 and reg==8 only (max 8 pushes between
        // checks; trigger qn>=8 -> qn <= 15 < QCAP always).
#pragma unroll
        for (int reg = 0; reg < 16; ++reg) {
            if (reg == 0 || reg == 8) {
                if (__any(qn >= 8)) {
                    int mx; WAVE_MAX(mx, qn)
                    DRAIN_QN(mx)
                }
            }
            float s = fmaf(-2.f, acc0[reg] + acc1[reg],
                           ((const float*)&sqA[reg >> 2])[reg & 3]);
            bool pass = s < tv[15];
            if (pass) {
                int cid = bgc + (reg & 3) + 8 * (reg >> 2);
                unsigned long long kk =
                    ((unsigned long long)__float_as_uint(s) << 32) | (unsigned)cid;
                q[qn * 256 + tid] = kk;
                qn += 1;
            }
        }
    }

    // final drain (wave-uniform; qn <= 15)
    {
        int mx; WAVE_MAX(mx, qn)
        DRAIN_QN(mx)
    }

    __syncthreads();   // queue region dead everywhere -> safe to alias as fink

    // ---- block-end merge: 4 lists/row -> 1 list/row via u64 keys ----
    {
        int rowl = 32 * wr + rloc;
        int li = wc * 2 + hi;            // list index 0..3
#pragma unroll
        for (int j = 0; j < 16; ++j)
            fink[rowl][li * 16 + j] =
                ((unsigned long long)monof(tv[j]) << 32) | (unsigned)ti[j];
    }
    __syncthreads();
    if (tid < 128) {                     // stage 1: merge list pairs (0,1) and (2,3)
        int row = tid & 63, pr = tid >> 6;
        int base = pr * 32;
        unsigned long long tk[16];
#pragma unroll
        for (int j = 0; j < 16; ++j) tk[j] = fink[row][base + j];
        unsigned long long worstk = tk[0];
#pragma unroll
        for (int j = 1; j < 16; ++j) worstk = (tk[j] > worstk) ? tk[j] : worstk;
        for (int e = 0; e < 16; ++e) {
            unsigned long long k = fink[row][base + 16 + e];
            if (k < worstk) {
                unsigned long long mx = tk[0]; int pos = 0;
#pragma unroll
                for (int j = 1; j < 16; ++j) {
                    bool g = tk[j] > mx; mx = g ? tk[j] : mx; pos = g ? j : pos;
                }
#pragma unroll
                for (int j = 0; j < 16; ++j)
                    if (j == pos) tk[j] = k;
                unsigned long long nw = tk[0];
#pragma unroll
                for (int j = 1; j < 16; ++j) nw = (tk[j] > nw) ? tk[j] : nw;
                worstk = nw;
            }
        }
#pragma unroll
        for (int j = 0; j < 16; ++j) fink[row][base + j] = tk[j];
    }
    __syncthreads();
    if (tid < 64) {                      // stage 2: merge (0+1) with (2+3), write out
        int row = tid;
        unsigned long long tk[16];
#pragma unroll
        for (int j = 0; j < 16; ++j) tk[j] = fink[row][j];
        unsigned long long worstk = tk[0];
#pragma unroll
        for (int j = 1; j < 16; ++j) worstk = (tk[j] > worstk) ? tk[j] : worstk;
        for (int e = 0; e < 16; ++e) {
            unsigned long long k = fink[row][32 + e];
            if (k < worstk) {
                unsigned long long mx = tk[0]; int pos = 0;
#pragma unroll
                for (int j = 1; j < 16; ++j) {
                    bool g = tk[j] > mx; mx = g ? tk[j] : mx; pos = g ? j : pos;
                }
#pragma unroll
                for (int j = 0; j < 16; ++j)
                    if (j == pos) tk[j] = k;
                unsigned long long nw = tk[0];
#pragma unroll
                for (int j = 1; j < 16; ++j) nw = (tk[j] > nw) ? tk[j] : nw;
                worstk = nw;
            }
        }
        size_t o = (((size_t)(bglob + r0 + row)) * NQ + half) * KNN;
#pragma unroll
        for (int j = 0; j < 16; ++j) {
            pv[o + j] = invmonof((unsigned)(tk[j] >> 32));
            pi[o + j] = (int)(unsigned)(tk[j] & 0xFFFFFFFFu);
        }
    }
}

// ---------------------------------------------------------------------------
// K1b: merge NQ=2 partial top-16 lists per row -> final idx (u64-key exact).
// ---------------------------------------------------------------------------
__global__ void merge_kernel(const float* __restrict__ pv, const int* __restrict__ pi,
                             int* __restrict__ idx_out) {
    __shared__ unsigned long long mk[128 * 33];
    int tid = threadIdx.x;
    int lr = tid & 127, q = tid >> 7;
    int row = blockIdx.x * 128 + lr;
    size_t o = ((size_t)row * NQ + q) * KNN;
#pragma unroll
    for (int j = 0; j < 16; ++j) {
        mk[lr * 33 + q * 16 + j] =
            ((unsigned long long)monof(pv[o + j]) << 32) | (unsigned)pi[o + j];
    }
    __syncthreads();
    if (tid < 128) {
        unsigned long long tk[16];
#pragma unroll
        for (int j = 0; j < 16; ++j) tk[j] = mk[tid * 33 + j];
        unsigned long long worstk = tk[0];
#pragma unroll
        for (int j = 1; j < 16; ++j) worstk = (tk[j] > worstk) ? tk[j] : worstk;
        for (int e = 16; e < 32; ++e) {
            unsigned long long k = mk[tid * 33 + e];
            if (k < worstk) {
                unsigned long long mx = tk[0]; int pos = 0;
#pragma unroll
                for (int j = 1; j < 16; ++j) {
                    bool g = tk[j] > mx; mx = g ? tk[j] : mx; pos = g ? j : pos;
                }
#pragma unroll
                for (int j = 0; j < 16; ++j)
                    if (j == pos) tk[j] = k;
                unsigned long long nw = tk[0];
#pragma unroll
                for (int j = 1; j < 16; ++j) nw = (tk[j] > nw) ? tk[j] : nw;
                worstk = nw;
            }
        }
        size_t oo = (size_t)tid * KNN + (size_t)blockIdx.x * 128 * KNN;
#pragma unroll
        for (int j = 0; j < 16; ++j)
            idx_out[oo + j] = (int)(unsigned)(tk[j] & 0xFFFFFFFFu);
    }
}

// ---------------------------------------------------------------------------
// K2: U = x @ (W1 - W2), V = x @ W2
// ---------------------------------------------------------------------------
__global__ void prep_UV(const float* __restrict__ x, const float* __restrict__ W,
                        float* __restrict__ U, float* __restrict__ V) {
    __shared__ float Ws[128][64];
    __shared__ float xs[4][64];
    int tid = threadIdx.x;
    for (int i = tid; i < 128 * 64; i += 256) ((float*)Ws)[i] = W[i];
    int p0 = blockIdx.x * 4;
    int r = tid >> 6, c = tid & 63;
    xs[r][c] = x[(size_t)(p0 + r) * C + c];
    __syncthreads();
    float u = 0.f, v = 0.f;
#pragma unroll
    for (int k = 0; k < 64; ++k) {
        float xv = xs[r][k];
        float w1 = Ws[k][c];
        float w2 = Ws[64 + k][c];
        u = fmaf(xv, w1 - w2, u);
        v = fmaf(xv, w2, v);
    }
    size_t o = (size_t)(p0 + r) * C + c;
    U[o] = u;
    V[o] = v;
}

// ---------------------------------------------------------------------------
// K3: BN stats
// ---------------------------------------------------------------------------
__global__ void stats_kernel(const float* __restrict__ U, const float* __restrict__ V,
                             const float* __restrict__ bias, const int* __restrict__ idx,
                             float* __restrict__ stats) {
    int tid = threadIdx.x;
    int c = tid & 63, kk = tid >> 6;
    int p0 = blockIdx.x * 32;
    float bc = bias[c];
    float sum = 0.f, sumsq = 0.f;
    for (int pp = 0; pp < 32; ++pp) {
        int p = p0 + pp;
        float u = U[(size_t)p * C + c] + bc;
#pragma unroll
        for (int k4 = 0; k4 < 4; ++k4) {
            int j = idx[(size_t)p * KNN + kk * 4 + k4];
            float h = u + V[(size_t)j * C + c];
            sum += h;
            sumsq = fmaf(h, h, sumsq);
        }
    }
    __shared__ float red[2][4][64];
    red[0][kk][c] = sum;
    red[1][kk][c] = sumsq;
    __syncthreads();
    if (tid < 64) {
        float s = red[0][0][tid] + red[0][1][tid] + red[0][2][tid] + red[0][3][tid];
        atomicAdd(&stats[tid], s);
    } else if (tid < 128) {
        int cc = tid - 64;
        float s = red[1][0][cc] + red[1][1][cc] + red[1][2][cc] + red[1][3][cc];
        atomicAdd(&stats[64 + cc], s);
    }
}

__global__ void finalize_kernel(const float* __restrict__ stats,
                                const float* __restrict__ gamma,
                                const float* __restrict__ beta,
                                float* __restrict__ sshift) {
    int c = threadIdx.x;
    const float N = (float)NEDGE;
    float mean = stats[c] / N;
    float var = stats[64 + c] / N - mean * mean;
    float s = gamma[c] * rsqrtf(var + EPSV);
    sshift[c] = s;
    sshift[64 + c] = beta[c] - mean * s;
}

// ---------------------------------------------------------------------------
// K5: out = lrelu(s*(U+b + max/min_k V[idx]) + t)  (monotone fusion of max_k)
// ---------------------------------------------------------------------------
__global__ void out_kernel(const float* __restrict__ U, const float* __restrict__ V,
                           const float* __restrict__ bias, const int* __restrict__ idx,
                           const float* __restrict__ sshift, float* __restrict__ out) {
    int tid = threadIdx.x;
    int c = tid & 63, g = tid >> 6;
    int p0 = blockIdx.x * 16;
    float s = sshift[c], t = sshift[64 + c];
    float bc = bias[c];
    for (int pp = g; pp < 16; pp += 4) {
        int p = p0 + pp;
        float mx = -FLT_MAX, mn = FLT_MAX;
#pragma unroll
        for (int k = 0; k < KNN; ++k) {
            int j = idx[(size_t)p * KNN + k];
            float v = V[(size_t)j * C + c];
            mx = fmaxf(mx, v);
            mn = fminf(mn, v);
        }
        float hsel = (s >= 0.f) ? mx : mn;
        float hn = fmaf(s, U[(size_t)p * C + c] + bc + hsel, t);
        out[(size_t)p * C + c] = (hn >= 0.f) ? hn : SLOPE * hn;
    }
}

// ---------------------------------------------------------------------------
extern "C" void kernel_launch(void* const* d_in, const int* in_sizes, int n_in,
                              void* d_out, int out_size, void* d_ws, size_t ws_size,
                              hipStream_t stream) {
    const float* x     = (const float*)d_in[0];
    const float* W     = (const float*)d_in[2];
    const float* bias  = (const float*)d_in[3];
    const float* gamma = (const float*)d_in[4];
    const float* beta  = (const float*)d_in[5];
    float* out = (float*)d_out;

    float* wsf    = (float*)d_ws;
    float* U      = wsf;
    float* V      = wsf + 2097152;
    uint4* xfh    = (uint4*)wsf;                   // aliases U/V, dead after knn
    uint4* xfm    = (uint4*)(wsf + 1048576);
    uint4* xfl    = (uint4*)(wsf + 2097152);
    float* sq     = wsf + 4194304;
    float* stats  = wsf + 4227072;
    float* sshift = wsf + 4227200;
    int*   idx    = (int*)(wsf + 4227328);
    float* pv     = wsf + 4751616;
    int*   pi     = (int*)(wsf + 5800192);

    hipLaunchKernelGGL(prep_frag, dim3(NPTS / 32), dim3(256), 0, stream, x, xfh, xfm, xfl, sq);
    hipLaunchKernelGGL(knn_kernel, dim3(BATCH * (P / 64) * NQ), dim3(256), 0, stream,
                       (const uint4*)xfh, (const uint4*)xfm, (const uint4*)xfl, sq, pv, pi);
    hipLaunchKernelGGL(merge_kernel, dim3(NPTS / 128), dim3(256), 0, stream, pv, pi, idx);
    hipLaunchKernelGGL(prep_UV, dim3(NPTS / 4), dim3(256), 0, stream, x, W, U, V);
    hipMemsetAsync(stats, 0, 128 * sizeof(float), stream);
    hipLaunchKernelGGL(stats_kernel, dim3(NPTS / 32), dim3(256), 0, stream, U, V, bias, idx, stats);
    hipLaunchKernelGGL(finalize_kernel, dim3(1), dim3(64), 0, stream, stats, gamma, beta, sshift);
    hipLaunchKernelGGL(out_kernel, dim3(NPTS / 16), dim3(256), 0, stream, U, V, bias, idx, sshift, out);
}

// Round 11
// 501.530 us; speedup vs baseline: 1.0510x; 1.0479x over previous
//
#include <hip/hip_runtime.h>
#include <cfloat>

#define BATCH 4
#define P 8192
#define C 64
#define KNN 16
#define NPTS (BATCH * P)        // 32768
#define NEDGE (NPTS * KNN)      // 524288
#define EPSV 1e-5f
#define SLOPE 0.2f
#define NQ 2                    // column-range split per row-tile
#define QCOLS (P / NQ)          // 4096 cols per block
#define QCAP 8                  // lane-private LDS queue depth

typedef __attribute__((ext_vector_type(8))) short bf16x8;
typedef __attribute__((ext_vector_type(16))) float f32x16;

// ---------------- workspace layout (float element offsets) ----------------
// U      : [NPTS][C]   @ 0          (2097152)   written AFTER knn
// V      : [NPTS][C]   @ 2097152    (2097152)   written AFTER knn
// xfh/xfm/xfl bf16 frags alias U/V region (dead after knn)
// sq     : [NPTS]      @ 4194304    (32768)
// stats  : [128]       @ 4227072
// idx    : int[NEDGE]  @ 4227328    (524288)
// pv     : [NPTS][NQ][16] float @ 4751616 (1048576)
// pi     : [NPTS][NQ][16] int   @ 5800192 (1048576)
// hsel   : [NPTS][C] float @ 4751616 (2097152) — aliases pv+pi (dead after merge)
// total = 6848768 floats = 26.1 MB

__device__ __forceinline__ unsigned short f2bf(float f) {
    unsigned u = __float_as_uint(f);
    u += 0x7FFFu + ((u >> 16) & 1u);
    return (unsigned short)(u >> 16);
}
__device__ __forceinline__ float bf2f(unsigned short s) {
    return __uint_as_float(((unsigned)s) << 16);
}
// monotone float<->uint map: monof(a) < monof(b)  <=>  a < b (finite floats)
__device__ __forceinline__ unsigned monof(float f) {
    unsigned u = __float_as_uint(f);
    return u ^ ((unsigned)((int)u >> 31) | 0x80000000u);
}
__device__ __forceinline__ float invmonof(unsigned k) {
    unsigned u = (k & 0x80000000u) ? (k ^ 0x80000000u) : ~k;
    return __uint_as_float(u);
}

// ---------------------------------------------------------------------------
// K0: fragment-layout 3-way bf16 split of x + exact fp32 row norms.
// ---------------------------------------------------------------------------
__global__ void prep_frag(const float* __restrict__ x, uint4* __restrict__ xfh,
                          uint4* __restrict__ xfm, uint4* __restrict__ xfl,
                          float* __restrict__ sq) {
    __shared__ float part[32][9];
    int tid = threadIdx.x;
    int ptl = tid >> 3, j8 = tid & 7;
    int g = blockIdx.x;
    int p = g * 32 + ptl;
    const float4* xp = (const float4*)(x + (size_t)p * C + j8 * 8);
    float4 a = xp[0], b = xp[1];
    float v[8] = {a.x, a.y, a.z, a.w, b.x, b.y, b.z, b.w};
    unsigned short hs[8], ms[8], ls[8];
    float ssum = 0.f;
#pragma unroll
    for (int e = 0; e < 8; ++e) {
        float xv = v[e];
        ssum = fmaf(xv, xv, ssum);
        unsigned short h = f2bf(xv);
        float r1 = xv - bf2f(h);
        unsigned short m = f2bf(r1);
        float r2 = r1 - bf2f(m);
        unsigned short l = f2bf(r2);
        hs[e] = h; ms[e] = m; ls[e] = l;
    }
    int dst = (g * 4 + (j8 >> 1)) * 64 + ptl + 32 * (j8 & 1);
    uint4 ph, pm, pl;
    ph.x = (unsigned)hs[0] | ((unsigned)hs[1] << 16);
    ph.y = (unsigned)hs[2] | ((unsigned)hs[3] << 16);
    ph.z = (unsigned)hs[4] | ((unsigned)hs[5] << 16);
    ph.w = (unsigned)hs[6] | ((unsigned)hs[7] << 16);
    pm.x = (unsigned)ms[0] | ((unsigned)ms[1] << 16);
    pm.y = (unsigned)ms[2] | ((unsigned)ms[3] << 16);
    pm.z = (unsigned)ms[4] | ((unsigned)ms[5] << 16);
    pm.w = (unsigned)ms[6] | ((unsigned)ms[7] << 16);
    pl.x = (unsigned)ls[0] | ((unsigned)ls[1] << 16);
    pl.y = (unsigned)ls[2] | ((unsigned)ls[3] << 16);
    pl.z = (unsigned)ls[4] | ((unsigned)ls[5] << 16);
    pl.w = (unsigned)ls[6] | ((unsigned)ls[7] << 16);
    xfh[dst] = ph; xfm[dst] = pm; xfl[dst] = pl;
    part[ptl][j8] = ssum;
    __syncthreads();
    if (j8 == 0) {
        float s = 0.f;
#pragma unroll
        for (int k = 0; k < 8; ++k) s += part[ptl][k];
        sq[p] = s;
    }
}

// sorted-shift insert into ASC tv[16]/ti[16]: precomputed bools, descending
// in-place shift, all-static indexing, ~85 independent VALU. Strict '<':
// equal values keep the earlier-inserted (lower stream position).
#define SORTED_INS16(MV, IDV)                                                  \
    {                                                                          \
        float _m = (MV); int _id = (IDV);                                      \
        bool c0 = _m < tv[0], c1 = _m < tv[1], c2 = _m < tv[2],                \
             c3 = _m < tv[3], c4 = _m < tv[4], c5 = _m < tv[5],                \
             c6 = _m < tv[6], c7 = _m < tv[7], c8 = _m < tv[8],                \
             c9 = _m < tv[9], c10 = _m < tv[10], c11 = _m < tv[11],            \
             c12 = _m < tv[12], c13 = _m < tv[13], c14 = _m < tv[14],          \
             c15 = _m < tv[15];                                                \
        tv[15] = c15 ? (c14 ? tv[14] : _m) : tv[15];                           \
        ti[15] = c15 ? (c14 ? ti[14] : _id) : ti[15];                          \
        tv[14] = c14 ? (c13 ? tv[13] : _m) : tv[14];                           \
        ti[14] = c14 ? (c13 ? ti[13] : _id) : ti[14];                          \
        tv[13] = c13 ? (c12 ? tv[12] : _m) : tv[13];                           \
        ti[13] = c13 ? (c12 ? ti[12] : _id) : ti[13];                          \
        tv[12] = c12 ? (c11 ? tv[11] : _m) : tv[12];                           \
        ti[12] = c12 ? (c11 ? ti[11] : _id) : ti[12];                          \
        tv[11] = c11 ? (c10 ? tv[10] : _m) : tv[11];                           \
        ti[11] = c11 ? (c10 ? ti[10] : _id) : ti[11];                          \
        tv[10] = c10 ? (c9 ? tv[9] : _m) : tv[10];                             \
        ti[10] = c10 ? (c9 ? ti[9] : _id) : ti[10];                            \
        tv[9] = c9 ? (c8 ? tv[8] : _m) : tv[9];                                \
        ti[9] = c9 ? (c8 ? ti[8] : _id) : ti[9];                               \
        tv[8] = c8 ? (c7 ? tv[7] : _m) : tv[8];                                \
        ti[8] = c8 ? (c7 ? ti[7] : _id) : ti[8];                               \
        tv[7] = c7 ? (c6 ? tv[6] : _m) : tv[7];                                \
        ti[7] = c7 ? (c6 ? ti[6] : _id) : ti[7];                               \
        tv[6] = c6 ? (c5 ? tv[5] : _m) : tv[6];                                \
        ti[6] = c6 ? (c5 ? ti[5] : _id) : ti[6];                               \
        tv[5] = c5 ? (c4 ? tv[4] : _m) : tv[5];                                \
        ti[5] = c5 ? (c4 ? ti[4] : _id) : ti[5];                               \
        tv[4] = c4 ? (c3 ? tv[3] : _m) : tv[4];                                \
        ti[4] = c4 ? (c3 ? ti[3] : _id) : ti[4];                               \
        tv[3] = c3 ? (c2 ? tv[2] : _m) : tv[3];                                \
        ti[3] = c3 ? (c2 ? ti[2] : _id) : ti[3];                               \
        tv[2] = c2 ? (c1 ? tv[1] : _m) : tv[2];                                \
        ti[2] = c2 ? (c1 ? ti[1] : _id) : ti[2];                               \
        tv[1] = c1 ? (c0 ? tv[0] : _m) : tv[1];                                \
        ti[1] = c1 ? (c0 ? ti[0] : _id) : ti[1];                               \
        tv[0] = c0 ? _m : tv[0];                                               \
        ti[0] = c0 ? _id : ti[0];                                              \
    }

// wave-uniform drain of the lane-private LDS queues: runtime (non-unrolled)
// QCAP-iteration loop; invalid slots insert FLT_MAX (no-op under strict '<').
// FIFO order = push order = column order -> tie semantics preserved.
#define DRAIN_Q                                                                \
    {                                                                          \
        _Pragma("nounroll")                                                    \
        for (int j = 0; j < QCAP; ++j) {                                       \
            unsigned long long kq = q[j * 256 + tid];                          \
            bool valid = (j < qn);                                             \
            float dv = valid ? __uint_as_float((unsigned)(kq >> 32)) : FLT_MAX;\
            int di = (int)(unsigned)(kq & 0xFFFFFFFFu);                        \
            SORTED_INS16(dv, di)                                               \
        }                                                                      \
        qn = 0;                                                                \
    }

// ---------------------------------------------------------------------------
// K1: KNN — r13 configuration verbatim (best measured: 403us, even residency
// at (256,4): grid 1024 = 4 blocks/CU x 256 CU exactly).
// r15 post-mortem: (256,3) raised VGPR 64->84 but knn stayed ~411 and the
// 256-block tail ran at 1 block/CU — the register-cap theory is dead; r13's
// config wins partly on clean grid residency. knn changes are frozen until
// disasm-level evidence identifies the ~57K cyc/wave residual.
// ---------------------------------------------------------------------------
__global__ __launch_bounds__(256, 4) void knn_kernel(const uint4* __restrict__ xfh,
                                                     const uint4* __restrict__ xfm,
                                                     const uint4* __restrict__ xfl,
                                                     const float* __restrict__ sq,
                                                     float* __restrict__ pv,
                                                     int* __restrict__ pi) {
    __shared__ unsigned long long smem[64 * 65];   // 33280 B
    unsigned long long* q = smem;                  // queue alias: [QCAP][256]
    unsigned long long (*fink)[65] = (unsigned long long (*)[65])smem;

    int tid = threadIdx.x;
    int b = blockIdx.x & 3;              // batch -> XCDs {b, b+4}: frags L2-resident
    int t = blockIdx.x >> 2;
    int tile = t & 127;
    int half = t >> 7;
    int bglob = b * P;
    int r0 = tile * 64;
    int w = tid >> 6, lane = tid & 63;
    int wr = w & 1, wc = w >> 1;
    int hi = lane >> 5;                  // col-offset selector (+4)
    int rloc = lane & 31;                // row owned by this lane (within wave tile)

    // persistent ROW fragments ("B" operand): rows r0 + 32*wr .. +32
    int gA = ((bglob + r0) >> 5) + wr;
    bf16x8 Rh[4], Rm[4], Rl[4];
#pragma unroll
    for (int kk = 0; kk < 4; ++kk) {
        Rh[kk] = __builtin_bit_cast(bf16x8, xfh[(gA * 4 + kk) * 64 + lane]);
        Rm[kk] = __builtin_bit_cast(bf16x8, xfm[(gA * 4 + kk) * 64 + lane]);
        Rl[kk] = __builtin_bit_cast(bf16x8, xfl[(gA * 4 + kk) * 64 + lane]);
    }

    // per-lane sorted top-16 (ASC) + LDS queue count
    float tv[16];
    int   ti[16];
#pragma unroll
    for (int j = 0; j < 16; ++j) { tv[j] = FLT_MAX; ti[j] = 0; }
    int qn = 0;

    int cw0 = half * QCOLS + wc * 2048;  // this wave's 2048-col range (64 chunks x 32)

    for (int chunk = 0; chunk < 64; ++chunk) {
        int c0 = cw0 + chunk * 32;
        int gB = (bglob + c0) >> 5;
        const uint4* ch = &xfh[(gB * 4) * 64 + lane];
        const uint4* cm = &xfm[(gB * 4) * 64 + lane];
        const uint4* cl = &xfl[(gB * 4) * 64 + lane];

        f32x16 acc0, acc1;
#pragma unroll
        for (int i = 0; i < 16; ++i) { acc0[i] = 0.f; acc1[i] = 0.f; }
#pragma unroll
        for (int kk = 0; kk < 4; ++kk) {
            bf16x8 Ch = __builtin_bit_cast(bf16x8, ch[kk * 64]);
            bf16x8 Cm = __builtin_bit_cast(bf16x8, cm[kk * 64]);
            bf16x8 Cl = __builtin_bit_cast(bf16x8, cl[kk * 64]);
            acc0 = __builtin_amdgcn_mfma_f32_32x32x16_bf16(Ch, Rh[kk], acc0, 0, 0, 0);
            acc1 = __builtin_amdgcn_mfma_f32_32x32x16_bf16(Ch, Rm[kk], acc1, 0, 0, 0);
            acc0 = __builtin_amdgcn_mfma_f32_32x32x16_bf16(Cm, Rh[kk], acc0, 0, 0, 0);
            acc1 = __builtin_amdgcn_mfma_f32_32x32x16_bf16(Cm, Rm[kk], acc1, 0, 0, 0);
            acc0 = __builtin_amdgcn_mfma_f32_32x32x16_bf16(Ch, Rl[kk], acc0, 0, 0, 0);
            acc1 = __builtin_amdgcn_mfma_f32_32x32x16_bf16(Cl, Rh[kk], acc1, 0, 0, 0);
        }

        // col norms for this lane's 16 cols (uniform per half-wave, L1-hit)
        int cb = c0 + 4 * hi;
        float4 sqA[4];
#pragma unroll
        for (int g4 = 0; g4 < 4; ++g4)
            sqA[g4] = *(const float4*)(&sq[bglob + cb + g4 * 8]);
        int bgc = bglob + cb;            // GLOBAL col id base

        // site loop: s' = sq_col - 2 x.y (sq_row dropped: rank-invariant)
#pragma unroll
        for (int reg = 0; reg < 16; ++reg) {
            float s = fmaf(-2.f, acc0[reg] + acc1[reg],
                           ((const float*)&sqA[reg >> 2])[reg & 3]);
            if (__any(qn == QCAP)) { DRAIN_Q }   // wave-uniform, batched
            bool pass = s < tv[15];
            if (pass) {
                int cid = bgc + (reg & 3) + 8 * (reg >> 2);
                unsigned long long kk =
                    ((unsigned long long)__float_as_uint(s) << 32) | (unsigned)cid;
                q[qn * 256 + tid] = kk;
                qn += 1;
            }
        }
    }

    // final drain (wave-uniform; qn <= QCAP)
    DRAIN_Q

    __syncthreads();   // queue region dead everywhere -> safe to alias as fink

    // ---- block-end merge: 4 lists/row -> 1 list/row via u64 keys ----
    {
        int rowl = 32 * wr + rloc;
        int li = wc * 2 + hi;            // list index 0..3
#pragma unroll
        for (int j = 0; j < 16; ++j)
            fink[rowl][li * 16 + j] =
                ((unsigned long long)monof(tv[j]) << 32) | (unsigned)ti[j];
    }
    __syncthreads();
    if (tid < 128) {                     // stage 1: merge list pairs (0,1) and (2,3)
        int row = tid & 63, pr = tid >> 6;
        int base = pr * 32;
        unsigned long long tk[16];
#pragma unroll
        for (int j = 0; j < 16; ++j) tk[j] = fink[row][base + j];
        unsigned long long worstk = tk[0];
#pragma unroll
        for (int j = 1; j < 16; ++j) worstk = (tk[j] > worstk) ? tk[j] : worstk;
        for (int e = 0; e < 16; ++e) {
            unsigned long long k = fink[row][base + 16 + e];
            if (k < worstk) {
                unsigned long long mx = tk[0]; int pos = 0;
#pragma unroll
                for (int j = 1; j < 16; ++j) {
                    bool g = tk[j] > mx; mx = g ? tk[j] : mx; pos = g ? j : pos;
                }
#pragma unroll
                for (int j = 0; j < 16; ++j)
                    if (j == pos) tk[j] = k;
                unsigned long long nw = tk[0];
#pragma unroll
                for (int j = 1; j < 16; ++j) nw = (tk[j] > nw) ? tk[j] : nw;
                worstk = nw;
            }
        }
#pragma unroll
        for (int j = 0; j < 16; ++j) fink[row][base + j] = tk[j];
    }
    __syncthreads();
    if (tid < 64) {                      // stage 2: merge (0+1) with (2+3), write out
        int row = tid;
        unsigned long long tk[16];
#pragma unroll
        for (int j = 0; j < 16; ++j) tk[j] = fink[row][j];
        unsigned long long worstk = tk[0];
#pragma unroll
        for (int j = 1; j < 16; ++j) worstk = (tk[j] > worstk) ? tk[j] : worstk;
        for (int e = 0; e < 16; ++e) {
            unsigned long long k = fink[row][32 + e];
            if (k < worstk) {
                unsigned long long mx = tk[0]; int pos = 0;
#pragma unroll
                for (int j = 1; j < 16; ++j) {
                    bool g = tk[j] > mx; mx = g ? tk[j] : mx; pos = g ? j : pos;
                }
#pragma unroll
                for (int j = 0; j < 16; ++j)
                    if (j == pos) tk[j] = k;
                unsigned long long nw = tk[0];
#pragma unroll
                for (int j = 1; j < 16; ++j) nw = (tk[j] > nw) ? tk[j] : nw;
                worstk = nw;
            }
        }
        size_t o = (((size_t)(bglob + r0 + row)) * NQ + half) * KNN;
#pragma unroll
        for (int j = 0; j < 16; ++j) {
            pv[o + j] = invmonof((unsigned)(tk[j] >> 32));
            pi[o + j] = (int)(unsigned)(tk[j] & 0xFFFFFFFFu);
        }
    }
}

// ---------------------------------------------------------------------------
// K1b: merge NQ=2 partial top-16 lists per row -> final idx (u64-key exact).
// ---------------------------------------------------------------------------
__global__ void merge_kernel(const float* __restrict__ pv, const int* __restrict__ pi,
                             int* __restrict__ idx_out) {
    __shared__ unsigned long long mk[128 * 33];
    int tid = threadIdx.x;
    int lr = tid & 127, q = tid >> 7;
    int row = blockIdx.x * 128 + lr;
    size_t o = ((size_t)row * NQ + q) * KNN;
#pragma unroll
    for (int j = 0; j < 16; ++j) {
        mk[lr * 33 + q * 16 + j] =
            ((unsigned long long)monof(pv[o + j]) << 32) | (unsigned)pi[o + j];
    }
    __syncthreads();
    if (tid < 128) {
        unsigned long long tk[16];
#pragma unroll
        for (int j = 0; j < 16; ++j) tk[j] = mk[tid * 33 + j];
        unsigned long long worstk = tk[0];
#pragma unroll
        for (int j = 1; j < 16; ++j) worstk = (tk[j] > worstk) ? tk[j] : worstk;
        for (int e = 16; e < 32; ++e) {
            unsigned long long k = mk[tid * 33 + e];
            if (k < worstk) {
                unsigned long long mx = tk[0]; int pos = 0;
#pragma unroll
                for (int j = 1; j < 16; ++j) {
                    bool g = tk[j] > mx; mx = g ? tk[j] : mx; pos = g ? j : pos;
                }
#pragma unroll
                for (int j = 0; j < 16; ++j)
                    if (j == pos) tk[j] = k;
                unsigned long long nw = tk[0];
#pragma unroll
                for (int j = 1; j < 16; ++j) nw = (tk[j] > nw) ? tk[j] : nw;
                worstk = nw;
            }
        }
        size_t oo = (size_t)tid * KNN + (size_t)blockIdx.x * 128 * KNN;
#pragma unroll
        for (int j = 0; j < 16; ++j)
            idx_out[oo + j] = (int)(unsigned)(tk[j] & 0xFFFFFFFFu);
    }
}

// ---------------------------------------------------------------------------
// K2: U = x @ (W1 - W2), V = x @ W2
// ---------------------------------------------------------------------------
__global__ void prep_UV(const float* __restrict__ x, const float* __restrict__ W,
                        float* __restrict__ U, float* __restrict__ V) {
    __shared__ float Ws[128][64];
    __shared__ float xs[4][64];
    int tid = threadIdx.x;
    for (int i = tid; i < 128 * 64; i += 256) ((float*)Ws)[i] = W[i];
    int p0 = blockIdx.x * 4;
    int r = tid >> 6, c = tid & 63;
    xs[r][c] = x[(size_t)(p0 + r) * C + c];
    __syncthreads();
    float u = 0.f, v = 0.f;
#pragma unroll
    for (int k = 0; k < 64; ++k) {
        float xv = xs[r][k];
        float w1 = Ws[k][c];
        float w2 = Ws[64 + k][c];
        u = fmaf(xv, w1 - w2, u);
        v = fmaf(xv, w2, v);
    }
    size_t o = (size_t)(p0 + r) * C + c;
    U[o] = u;
    V[o] = v;
}

// ---------------------------------------------------------------------------
// K3: BN stats + fused neighbor max/min selection (r16).
// Thread (c, g=tid>>6) handles points p0+g, p0+g+4, ... (8 points x 16 k).
// Gathers V[idx] once: accumulates BN sum/sumsq AND computes
// hsel = (U+b) + (gamma>=0 ? max_k V : min_k V). sign(s)=sign(gamma)
// (rsqrt>0); gamma==0 -> s=0, hsel irrelevant. out_kernel never re-gathers.
// ---------------------------------------------------------------------------
__global__ void stats_kernel(const float* __restrict__ U, const float* __restrict__ V,
                             const float* __restrict__ bias,
                             const float* __restrict__ gamma,
                             const int* __restrict__ idx,
                             float* __restrict__ stats, float* __restrict__ hsel) {
    int tid = threadIdx.x;
    int c = tid & 63, g = tid >> 6;
    int p0 = blockIdx.x * 32;
    float bc = bias[c];
    bool gpos = (gamma[c] >= 0.f);
    float sum = 0.f, sumsq = 0.f;
    for (int pp = g; pp < 32; pp += 4) {
        int p = p0 + pp;
        float u = U[(size_t)p * C + c] + bc;
        float mx = -FLT_MAX, mn = FLT_MAX;
#pragma unroll
        for (int k = 0; k < KNN; ++k) {
            int j = idx[(size_t)p * KNN + k];
            float v = V[(size_t)j * C + c];
            float h = u + v;
            sum += h;
            sumsq = fmaf(h, h, sumsq);
            mx = fmaxf(mx, v);
            mn = fminf(mn, v);
        }
        hsel[(size_t)p * C + c] = u + (gpos ? mx : mn);
    }
    __shared__ float red[2][4][64];
    red[0][g][c] = sum;
    red[1][g][c] = sumsq;
    __syncthreads();
    if (tid < 64) {
        float s = red[0][0][tid] + red[0][1][tid] + red[0][2][tid] + red[0][3][tid];
        atomicAdd(&stats[tid], s);
    } else if (tid < 128) {
        int cc = tid - 64;
        float s = red[1][0][cc] + red[1][1][cc] + red[1][2][cc] + red[1][3][cc];
        atomicAdd(&stats[64 + cc], s);
    }
}

// ---------------------------------------------------------------------------
// K5: out = lrelu(s*hsel + t) — pure float4 streaming; finalize folded in
// (each block recomputes s,t from stats in 64 lanes; removes a launch).
// ---------------------------------------------------------------------------
__global__ void out_kernel(const float* __restrict__ hsel,
                           const float* __restrict__ stats,
                           const float* __restrict__ gamma,
                           const float* __restrict__ beta,
                           float* __restrict__ out) {
    __shared__ float sS[64], sT[64];
    int tid = threadIdx.x;
    if (tid < 64) {
        const float N = (float)NEDGE;
        float mean = stats[tid] / N;
        float var = stats[64 + tid] / N - mean * mean;
        float s = gamma[tid] * rsqrtf(var + EPSV);
        sS[tid] = s;
        sT[tid] = beta[tid] - mean * s;
    }
    __syncthreads();
    // 2M floats = 524288 float4; grid 1024 x 256 threads x 2 float4 each.
    int gid = blockIdx.x * 256 + tid;
#pragma unroll
    for (int r = 0; r < 2; ++r) {
        size_t i4 = (size_t)gid + (size_t)r * 262144;
        size_t i = i4 * 4;
        int c0 = (int)(i & 63);
        float4 h4 = *(const float4*)&hsel[i];
        float4 s4 = *(const float4*)&sS[c0];
        float4 t4 = *(const float4*)&sT[c0];
        float4 o4;
        float hn;
        hn = fmaf(s4.x, h4.x, t4.x); o4.x = (hn >= 0.f) ? hn : SLOPE * hn;
        hn = fmaf(s4.y, h4.y, t4.y); o4.y = (hn >= 0.f) ? hn : SLOPE * hn;
        hn = fmaf(s4.z, h4.z, t4.z); o4.z = (hn >= 0.f) ? hn : SLOPE * hn;
        hn = fmaf(s4.w, h4.w, t4.w); o4.w = (hn >= 0.f) ? hn : SLOPE * hn;
        *(float4*)&out[i] = o4;
    }
}

// ---------------------------------------------------------------------------
extern "C" void kernel_launch(void* const* d_in, const int* in_sizes, int n_in,
                              void* d_out, int out_size, void* d_ws, size_t ws_size,
                              hipStream_t stream) {
    const float* x     = (const float*)d_in[0];
    const float* W     = (const float*)d_in[2];
    const float* bias  = (const float*)d_in[3];
    const float* gamma = (const float*)d_in[4];
    const float* beta  = (const float*)d_in[5];
    float* out = (float*)d_out;

    float* wsf    = (float*)d_ws;
    float* U      = wsf;
    float* V      = wsf + 2097152;
    uint4* xfh    = (uint4*)wsf;                   // aliases U/V, dead after knn
    uint4* xfm    = (uint4*)(wsf + 1048576);
    uint4* xfl    = (uint4*)(wsf + 2097152);
    float* sq     = wsf + 4194304;
    float* stats  = wsf + 4227072;
    int*   idx    = (int*)(wsf + 4227328);
    float* pv     = wsf + 4751616;
    int*   pi     = (int*)(wsf + 5800192);
    float* hsel   = wsf + 4751616;                 // aliases pv+pi (dead after merge)

    hipLaunchKernelGGL(prep_frag, dim3(NPTS / 32), dim3(256), 0, stream, x, xfh, xfm, xfl, sq);
    hipLaunchKernelGGL(knn_kernel, dim3(BATCH * (P / 64) * NQ), dim3(256), 0, stream,
                       (const uint4*)xfh, (const uint4*)xfm, (const uint4*)xfl, sq, pv, pi);
    hipLaunchKernelGGL(merge_kernel, dim3(NPTS / 128), dim3(256), 0, stream, pv, pi, idx);
    hipLaunchKernelGGL(prep_UV, dim3(NPTS / 4), dim3(256), 0, stream, x, W, U, V);
    hipMemsetAsync(stats, 0, 128 * sizeof(float), stream);
    hipLaunchKernelGGL(stats_kernel, dim3(NPTS / 32), dim3(256), 0, stream,
                       U, V, bias, gamma, idx, stats, hsel);
    hipLaunchKernelGGL(out_kernel, dim3(1024), dim3(256), 0, stream,
                       hsel, stats, gamma, beta, out);
}

// Round 12
// 492.331 us; speedup vs baseline: 1.0706x; 1.0187x over previous
//
#include <hip/hip_runtime.h>
#include <cfloat>

#define BATCH 4
#define P 8192
#define C 64
#define KNN 16
#define NPTS (BATCH * P)        // 32768
#define NEDGE (NPTS * KNN)      // 524288
#define EPSV 1e-5f
#define SLOPE 0.2f
#define NQ 2                    // column-range split per row-tile
#define QCOLS (P / NQ)          // 4096 cols per block
#define QCAP 8                  // lane-private LDS queue depth

typedef __attribute__((ext_vector_type(8))) short bf16x8;
typedef __attribute__((ext_vector_type(16))) float f32x16;

// ---------------- workspace layout (float element offsets) ----------------
// U      : [NPTS][C]   @ 0          (2097152)   written AFTER knn
// V      : [NPTS][C]   @ 2097152    (2097152)   written AFTER knn
// xfh/xfm/xfl bf16 frags alias U/V region (dead after knn)
// sq     : [NPTS]      @ 4194304    (32768)
// stats  : [128]       @ 4227072
// idx    : int[NEDGE]  @ 4227328    (524288)
// pv     : [NPTS][NQ][16] float @ 4751616 (1048576)
// pi     : [NPTS][NQ][16] int   @ 5800192 (1048576)
// hsel   : [NPTS][C] float @ 4751616 (2097152) — aliases pv+pi (dead after merge)
// total = 6848768 floats = 26.1 MB

__device__ __forceinline__ unsigned short f2bf(float f) {
    unsigned u = __float_as_uint(f);
    u += 0x7FFFu + ((u >> 16) & 1u);
    return (unsigned short)(u >> 16);
}
__device__ __forceinline__ float bf2f(unsigned short s) {
    return __uint_as_float(((unsigned)s) << 16);
}
// monotone float<->uint map: monof(a) < monof(b)  <=>  a < b (finite floats)
__device__ __forceinline__ unsigned monof(float f) {
    unsigned u = __float_as_uint(f);
    return u ^ ((unsigned)((int)u >> 31) | 0x80000000u);
}
__device__ __forceinline__ float invmonof(unsigned k) {
    unsigned u = (k & 0x80000000u) ? (k ^ 0x80000000u) : ~k;
    return __uint_as_float(u);
}

// ---------------------------------------------------------------------------
// K0: fragment-layout 3-way bf16 split of x + exact fp32 row norms.
// ---------------------------------------------------------------------------
__global__ void prep_frag(const float* __restrict__ x, uint4* __restrict__ xfh,
                          uint4* __restrict__ xfm, uint4* __restrict__ xfl,
                          float* __restrict__ sq) {
    __shared__ float part[32][9];
    int tid = threadIdx.x;
    int ptl = tid >> 3, j8 = tid & 7;
    int g = blockIdx.x;
    int p = g * 32 + ptl;
    const float4* xp = (const float4*)(x + (size_t)p * C + j8 * 8);
    float4 a = xp[0], b = xp[1];
    float v[8] = {a.x, a.y, a.z, a.w, b.x, b.y, b.z, b.w};
    unsigned short hs[8], ms[8], ls[8];
    float ssum = 0.f;
#pragma unroll
    for (int e = 0; e < 8; ++e) {
        float xv = v[e];
        ssum = fmaf(xv, xv, ssum);
        unsigned short h = f2bf(xv);
        float r1 = xv - bf2f(h);
        unsigned short m = f2bf(r1);
        float r2 = r1 - bf2f(m);
        unsigned short l = f2bf(r2);
        hs[e] = h; ms[e] = m; ls[e] = l;
    }
    int dst = (g * 4 + (j8 >> 1)) * 64 + ptl + 32 * (j8 & 1);
    uint4 ph, pm, pl;
    ph.x = (unsigned)hs[0] | ((unsigned)hs[1] << 16);
    ph.y = (unsigned)hs[2] | ((unsigned)hs[3] << 16);
    ph.z = (unsigned)hs[4] | ((unsigned)hs[5] << 16);
    ph.w = (unsigned)hs[6] | ((unsigned)hs[7] << 16);
    pm.x = (unsigned)ms[0] | ((unsigned)ms[1] << 16);
    pm.y = (unsigned)ms[2] | ((unsigned)ms[3] << 16);
    pm.z = (unsigned)ms[4] | ((unsigned)ms[5] << 16);
    pm.w = (unsigned)ms[6] | ((unsigned)ms[7] << 16);
    pl.x = (unsigned)ls[0] | ((unsigned)ls[1] << 16);
    pl.y = (unsigned)ls[2] | ((unsigned)ls[3] << 16);
    pl.z = (unsigned)ls[4] | ((unsigned)ls[5] << 16);
    pl.w = (unsigned)ls[6] | ((unsigned)ls[7] << 16);
    xfh[dst] = ph; xfm[dst] = pm; xfl[dst] = pl;
    part[ptl][j8] = ssum;
    __syncthreads();
    if (j8 == 0) {
        float s = 0.f;
#pragma unroll
        for (int k = 0; k < 8; ++k) s += part[ptl][k];
        sq[p] = s;
    }
}

// sorted-shift insert into ASC tv[16]/ti[16]: precomputed bools, descending
// in-place shift, all-static indexing, ~85 independent VALU. Strict '<':
// equal values keep the earlier-inserted (lower stream position).
#define SORTED_INS16(MV, IDV)                                                  \
    {                                                                          \
        float _m = (MV); int _id = (IDV);                                      \
        bool c0 = _m < tv[0], c1 = _m < tv[1], c2 = _m < tv[2],                \
             c3 = _m < tv[3], c4 = _m < tv[4], c5 = _m < tv[5],                \
             c6 = _m < tv[6], c7 = _m < tv[7], c8 = _m < tv[8],                \
             c9 = _m < tv[9], c10 = _m < tv[10], c11 = _m < tv[11],            \
             c12 = _m < tv[12], c13 = _m < tv[13], c14 = _m < tv[14],          \
             c15 = _m < tv[15];                                                \
        tv[15] = c15 ? (c14 ? tv[14] : _m) : tv[15];                           \
        ti[15] = c15 ? (c14 ? ti[14] : _id) : ti[15];                          \
        tv[14] = c14 ? (c13 ? tv[13] : _m) : tv[14];                           \
        ti[14] = c14 ? (c13 ? ti[13] : _id) : ti[14];                          \
        tv[13] = c13 ? (c12 ? tv[12] : _m) : tv[13];                           \
        ti[13] = c13 ? (c12 ? ti[12] : _id) : ti[13];                          \
        tv[12] = c12 ? (c11 ? tv[11] : _m) : tv[12];                           \
        ti[12] = c12 ? (c11 ? ti[11] : _id) : ti[12];                          \
        tv[11] = c11 ? (c10 ? tv[10] : _m) : tv[11];                           \
        ti[11] = c11 ? (c10 ? ti[10] : _id) : ti[11];                          \
        tv[10] = c10 ? (c9 ? tv[9] : _m) : tv[10];                             \
        ti[10] = c10 ? (c9 ? ti[9] : _id) : ti[10];                            \
        tv[9] = c9 ? (c8 ? tv[8] : _m) : tv[9];                                \
        ti[9] = c9 ? (c8 ? ti[8] : _id) : ti[9];                               \
        tv[8] = c8 ? (c7 ? tv[7] : _m) : tv[8];                                \
        ti[8] = c8 ? (c7 ? ti[7] : _id) : ti[8];                               \
        tv[7] = c7 ? (c6 ? tv[6] : _m) : tv[7];                                \
        ti[7] = c7 ? (c6 ? ti[6] : _id) : ti[7];                               \
        tv[6] = c6 ? (c5 ? tv[5] : _m) : tv[6];                                \
        ti[6] = c6 ? (c5 ? ti[5] : _id) : ti[6];                               \
        tv[5] = c5 ? (c4 ? tv[4] : _m) : tv[5];                                \
        ti[5] = c5 ? (c4 ? ti[4] : _id) : ti[5];                               \
        tv[4] = c4 ? (c3 ? tv[3] : _m) : tv[4];                                \
        ti[4] = c4 ? (c3 ? ti[3] : _id) : ti[4];                               \
        tv[3] = c3 ? (c2 ? tv[2] : _m) : tv[3];                                \
        ti[3] = c3 ? (c2 ? ti[2] : _id) : ti[3];                               \
        tv[2] = c2 ? (c1 ? tv[1] : _m) : tv[2];                                \
        ti[2] = c2 ? (c1 ? ti[1] : _id) : ti[2];                               \
        tv[1] = c1 ? (c0 ? tv[0] : _m) : tv[1];                                \
        ti[1] = c1 ? (c0 ? ti[0] : _id) : ti[1];                               \
        tv[0] = c0 ? _m : tv[0];                                               \
        ti[0] = c0 ? _id : ti[0];                                              \
    }

// wave-uniform drain of the lane-private LDS queues: runtime (non-unrolled)
// QCAP-iteration loop; invalid slots insert FLT_MAX (no-op under strict '<').
// FIFO order = push order = column order -> tie semantics preserved.
#define DRAIN_Q                                                                \
    {                                                                          \
        _Pragma("nounroll")                                                    \
        for (int j = 0; j < QCAP; ++j) {                                       \
            unsigned long long kq = q[j * 256 + tid];                          \
            bool valid = (j < qn);                                             \
            float dv = valid ? __uint_as_float((unsigned)(kq >> 32)) : FLT_MAX;\
            int di = (int)(unsigned)(kq & 0xFFFFFFFFu);                        \
            SORTED_INS16(dv, di)                                               \
        }                                                                      \
        qn = 0;                                                                \
    }

// selection pass over the staged (previous-chunk) scores. Same gate/push/
// drain logic as r13; cid reconstructed from the staged base.
#define SELECT16(SARR, BGC)                                                    \
    _Pragma("unroll")                                                          \
    for (int reg = 0; reg < 16; ++reg) {                                       \
        float s = (SARR)[reg];                                                 \
        if (__any(qn == QCAP)) { DRAIN_Q }                                     \
        bool pass = s < tv[15];                                                \
        if (pass) {                                                            \
            int cid = (BGC) + (reg & 3) + 8 * (reg >> 2);                      \
            unsigned long long kk =                                            \
                ((unsigned long long)__float_as_uint(s) << 32) | (unsigned)cid;\
            q[qn * 256 + tid] = kk;                                            \
            qn += 1;                                                           \
        }                                                                      \
    }

// ---------------------------------------------------------------------------
// K1: KNN r17 — r13 skeleton + staged-score pipeline + single accumulator.
//
// r13/r14/r15 post-mortem: three selection-SCHEDULING theories all landed at
// ~407us. Remaining explanation: the chunk body is a serial chain
// loads -> 24 MFMA -> acc read -> selection; selection VALU can't overlap
// the same chunk's MFMA drain (it reads acc), and 4 waves/SIMD can't fill
// the gap, so phases ADD instead of overlapping (VALU 49% + Mfma 23%, both
// unsaturated).
//
// r17 (pre-committed kill: knn >= 385us -> declare family floor):
//  * scores staged to sPrev[16] regs; SELECT16 runs on the PREVIOUS chunk's
//    scores -> no dependence on this chunk's acc -> VALU overlaps MFMA
//    (separate pipes, m114). Epilogue selects the last chunk. Per-lane
//    stream order (ascending column) and FIFO tie semantics unchanged.
//  * single f32x16 acc: all 6 split-products accumulate into one chain
//    (same product set, fp32 order change ~1ulp; absmax margin 6.8x).
//    Frees 16 AGPR + 16 inits + 16 adds/chunk -> sPrev fits (256,4):
//    ~108 arch VGPR + 16 AGPR = 124 <= 128.
// ---------------------------------------------------------------------------
__global__ __launch_bounds__(256, 4) void knn_kernel(const uint4* __restrict__ xfh,
                                                     const uint4* __restrict__ xfm,
                                                     const uint4* __restrict__ xfl,
                                                     const float* __restrict__ sq,
                                                     float* __restrict__ pv,
                                                     int* __restrict__ pi) {
    __shared__ unsigned long long smem[64 * 65];   // 33280 B
    unsigned long long* q = smem;                  // queue alias: [QCAP][256]
    unsigned long long (*fink)[65] = (unsigned long long (*)[65])smem;

    int tid = threadIdx.x;
    int b = blockIdx.x & 3;              // batch -> XCDs {b, b+4}: frags L2-resident
    int t = blockIdx.x >> 2;
    int tile = t & 127;
    int half = t >> 7;
    int bglob = b * P;
    int r0 = tile * 64;
    int w = tid >> 6, lane = tid & 63;
    int wr = w & 1, wc = w >> 1;
    int hi = lane >> 5;                  // col-offset selector (+4)
    int rloc = lane & 31;                // row owned by this lane (within wave tile)

    // persistent ROW fragments ("B" operand): rows r0 + 32*wr .. +32
    int gA = ((bglob + r0) >> 5) + wr;
    bf16x8 Rh[4], Rm[4], Rl[4];
#pragma unroll
    for (int kk = 0; kk < 4; ++kk) {
        Rh[kk] = __builtin_bit_cast(bf16x8, xfh[(gA * 4 + kk) * 64 + lane]);
        Rm[kk] = __builtin_bit_cast(bf16x8, xfm[(gA * 4 + kk) * 64 + lane]);
        Rl[kk] = __builtin_bit_cast(bf16x8, xfl[(gA * 4 + kk) * 64 + lane]);
    }

    // per-lane sorted top-16 (ASC) + LDS queue count + staged scores
    float tv[16];
    int   ti[16];
#pragma unroll
    for (int j = 0; j < 16; ++j) { tv[j] = FLT_MAX; ti[j] = 0; }
    int qn = 0;
    float sPrev[16];
#pragma unroll
    for (int j = 0; j < 16; ++j) sPrev[j] = FLT_MAX;  // gate never passes
    int prevBgc = 0;

    int cw0 = half * QCOLS + wc * 2048;  // this wave's 2048-col range (64 chunks x 32)

    for (int chunk = 0; chunk < 64; ++chunk) {
        int c0 = cw0 + chunk * 32;
        int gB = (bglob + c0) >> 5;
        const uint4* ch = &xfh[(gB * 4) * 64 + lane];
        const uint4* cm = &xfm[(gB * 4) * 64 + lane];
        const uint4* cl = &xfl[(gB * 4) * 64 + lane];

        f32x16 acc;
#pragma unroll
        for (int i = 0; i < 16; ++i) acc[i] = 0.f;
#pragma unroll
        for (int kk = 0; kk < 4; ++kk) {
            bf16x8 Ch = __builtin_bit_cast(bf16x8, ch[kk * 64]);
            bf16x8 Cm = __builtin_bit_cast(bf16x8, cm[kk * 64]);
            bf16x8 Cl = __builtin_bit_cast(bf16x8, cl[kk * 64]);
            acc = __builtin_amdgcn_mfma_f32_32x32x16_bf16(Ch, Rh[kk], acc, 0, 0, 0);
            acc = __builtin_amdgcn_mfma_f32_32x32x16_bf16(Ch, Rm[kk], acc, 0, 0, 0);
            acc = __builtin_amdgcn_mfma_f32_32x32x16_bf16(Cm, Rh[kk], acc, 0, 0, 0);
            acc = __builtin_amdgcn_mfma_f32_32x32x16_bf16(Cm, Rm[kk], acc, 0, 0, 0);
            acc = __builtin_amdgcn_mfma_f32_32x32x16_bf16(Ch, Rl[kk], acc, 0, 0, 0);
            acc = __builtin_amdgcn_mfma_f32_32x32x16_bf16(Cl, Rh[kk], acc, 0, 0, 0);
        }

        // selection on the PREVIOUS chunk's staged scores: no dependence on
        // acc -> issues while this chunk's MFMAs execute (VALU || MFMA pipes)
        SELECT16(sPrev, prevBgc)

        // col norms for this lane's 16 cols (uniform per half-wave, L1-hit)
        int cb = c0 + 4 * hi;
        float4 sqA[4];
#pragma unroll
        for (int g4 = 0; g4 < 4; ++g4)
            sqA[g4] = *(const float4*)(&sq[bglob + cb + g4 * 8]);

        // stage this chunk's scores: s' = sq_col - 2 x.y (sq_row dropped)
#pragma unroll
        for (int reg = 0; reg < 16; ++reg)
            sPrev[reg] = fmaf(-2.f, acc[reg],
                              ((const float*)&sqA[reg >> 2])[reg & 3]);
        prevBgc = bglob + cb;
    }

    // epilogue: select the last chunk, then final drain (qn <= QCAP)
    SELECT16(sPrev, prevBgc)
    DRAIN_Q

    __syncthreads();   // queue region dead everywhere -> safe to alias as fink

    // ---- block-end merge: 4 lists/row -> 1 list/row via u64 keys ----
    {
        int rowl = 32 * wr + rloc;
        int li = wc * 2 + hi;            // list index 0..3
#pragma unroll
        for (int j = 0; j < 16; ++j)
            fink[rowl][li * 16 + j] =
                ((unsigned long long)monof(tv[j]) << 32) | (unsigned)ti[j];
    }
    __syncthreads();
    if (tid < 128) {                     // stage 1: merge list pairs (0,1) and (2,3)
        int row = tid & 63, pr = tid >> 6;
        int base = pr * 32;
        unsigned long long tk[16];
#pragma unroll
        for (int j = 0; j < 16; ++j) tk[j] = fink[row][base + j];
        unsigned long long worstk = tk[0];
#pragma unroll
        for (int j = 1; j < 16; ++j) worstk = (tk[j] > worstk) ? tk[j] : worstk;
        for (int e = 0; e < 16; ++e) {
            unsigned long long k = fink[row][base + 16 + e];
            if (k < worstk) {
                unsigned long long mx = tk[0]; int pos = 0;
#pragma unroll
                for (int j = 1; j < 16; ++j) {
                    bool g = tk[j] > mx; mx = g ? tk[j] : mx; pos = g ? j : pos;
                }
#pragma unroll
                for (int j = 0; j < 16; ++j)
                    if (j == pos) tk[j] = k;
                unsigned long long nw = tk[0];
#pragma unroll
                for (int j = 1; j < 16; ++j) nw = (tk[j] > nw) ? tk[j] : nw;
                worstk = nw;
            }
        }
#pragma unroll
        for (int j = 0; j < 16; ++j) fink[row][base + j] = tk[j];
    }
    __syncthreads();
    if (tid < 64) {                      // stage 2: merge (0+1) with (2+3), write out
        int row = tid;
        unsigned long long tk[16];
#pragma unroll
        for (int j = 0; j < 16; ++j) tk[j] = fink[row][j];
        unsigned long long worstk = tk[0];
#pragma unroll
        for (int j = 1; j < 16; ++j) worstk = (tk[j] > worstk) ? tk[j] : worstk;
        for (int e = 0; e < 16; ++e) {
            unsigned long long k = fink[row][32 + e];
            if (k < worstk) {
                unsigned long long mx = tk[0]; int pos = 0;
#pragma unroll
                for (int j = 1; j < 16; ++j) {
                    bool g = tk[j] > mx; mx = g ? tk[j] : mx; pos = g ? j : pos;
                }
#pragma unroll
                for (int j = 0; j < 16; ++j)
                    if (j == pos) tk[j] = k;
                unsigned long long nw = tk[0];
#pragma unroll
                for (int j = 1; j < 16; ++j) nw = (tk[j] > nw) ? tk[j] : nw;
                worstk = nw;
            }
        }
        size_t o = (((size_t)(bglob + r0 + row)) * NQ + half) * KNN;
#pragma unroll
        for (int j = 0; j < 16; ++j) {
            pv[o + j] = invmonof((unsigned)(tk[j] >> 32));
            pi[o + j] = (int)(unsigned)(tk[j] & 0xFFFFFFFFu);
        }
    }
}

// ---------------------------------------------------------------------------
// K1b: merge NQ=2 partial top-16 lists per row -> final idx (u64-key exact).
// ---------------------------------------------------------------------------
__global__ void merge_kernel(const float* __restrict__ pv, const int* __restrict__ pi,
                             int* __restrict__ idx_out) {
    __shared__ unsigned long long mk[128 * 33];
    int tid = threadIdx.x;
    int lr = tid & 127, q = tid >> 7;
    int row = blockIdx.x * 128 + lr;
    size_t o = ((size_t)row * NQ + q) * KNN;
#pragma unroll
    for (int j = 0; j < 16; ++j) {
        mk[lr * 33 + q * 16 + j] =
            ((unsigned long long)monof(pv[o + j]) << 32) | (unsigned)pi[o + j];
    }
    __syncthreads();
    if (tid < 128) {
        unsigned long long tk[16];
#pragma unroll
        for (int j = 0; j < 16; ++j) tk[j] = mk[tid * 33 + j];
        unsigned long long worstk = tk[0];
#pragma unroll
        for (int j = 1; j < 16; ++j) worstk = (tk[j] > worstk) ? tk[j] : worstk;
        for (int e = 16; e < 32; ++e) {
            unsigned long long k = mk[tid * 33 + e];
            if (k < worstk) {
                unsigned long long mx = tk[0]; int pos = 0;
#pragma unroll
                for (int j = 1; j < 16; ++j) {
                    bool g = tk[j] > mx; mx = g ? tk[j] : mx; pos = g ? j : pos;
                }
#pragma unroll
                for (int j = 0; j < 16; ++j)
                    if (j == pos) tk[j] = k;
                unsigned long long nw = tk[0];
#pragma unroll
                for (int j = 1; j < 16; ++j) nw = (tk[j] > nw) ? tk[j] : nw;
                worstk = nw;
            }
        }
        size_t oo = (size_t)tid * KNN + (size_t)blockIdx.x * 128 * KNN;
#pragma unroll
        for (int j = 0; j < 16; ++j)
            idx_out[oo + j] = (int)(unsigned)(tk[j] & 0xFFFFFFFFu);
    }
}

// ---------------------------------------------------------------------------
// K2: U = x @ (W1 - W2), V = x @ W2
// ---------------------------------------------------------------------------
__global__ void prep_UV(const float* __restrict__ x, const float* __restrict__ W,
                        float* __restrict__ U, float* __restrict__ V) {
    __shared__ float Ws[128][64];
    __shared__ float xs[4][64];
    int tid = threadIdx.x;
    for (int i = tid; i < 128 * 64; i += 256) ((float*)Ws)[i] = W[i];
    int p0 = blockIdx.x * 4;
    int r = tid >> 6, c = tid & 63;
    xs[r][c] = x[(size_t)(p0 + r) * C + c];
    __syncthreads();
    float u = 0.f, v = 0.f;
#pragma unroll
    for (int k = 0; k < 64; ++k) {
        float xv = xs[r][k];
        float w1 = Ws[k][c];
        float w2 = Ws[64 + k][c];
        u = fmaf(xv, w1 - w2, u);
        v = fmaf(xv, w2, v);
    }
    size_t o = (size_t)(p0 + r) * C + c;
    U[o] = u;
    V[o] = v;
}

// ---------------------------------------------------------------------------
// K3: BN stats + fused neighbor max/min selection (r16).
// Gathers V[idx] once: accumulates BN sum/sumsq AND computes
// hsel = (U+b) + (gamma>=0 ? max_k V : min_k V). sign(s)=sign(gamma).
// ---------------------------------------------------------------------------
__global__ void stats_kernel(const float* __restrict__ U, const float* __restrict__ V,
                             const float* __restrict__ bias,
                             const float* __restrict__ gamma,
                             const int* __restrict__ idx,
                             float* __restrict__ stats, float* __restrict__ hsel) {
    int tid = threadIdx.x;
    int c = tid & 63, g = tid >> 6;
    int p0 = blockIdx.x * 32;
    float bc = bias[c];
    bool gpos = (gamma[c] >= 0.f);
    float sum = 0.f, sumsq = 0.f;
    for (int pp = g; pp < 32; pp += 4) {
        int p = p0 + pp;
        float u = U[(size_t)p * C + c] + bc;
        float mx = -FLT_MAX, mn = FLT_MAX;
#pragma unroll
        for (int k = 0; k < KNN; ++k) {
            int j = idx[(size_t)p * KNN + k];
            float v = V[(size_t)j * C + c];
            float h = u + v;
            sum += h;
            sumsq = fmaf(h, h, sumsq);
            mx = fmaxf(mx, v);
            mn = fminf(mn, v);
        }
        hsel[(size_t)p * C + c] = u + (gpos ? mx : mn);
    }
    __shared__ float red[2][4][64];
    red[0][g][c] = sum;
    red[1][g][c] = sumsq;
    __syncthreads();
    if (tid < 64) {
        float s = red[0][0][tid] + red[0][1][tid] + red[0][2][tid] + red[0][3][tid];
        atomicAdd(&stats[tid], s);
    } else if (tid < 128) {
        int cc = tid - 64;
        float s = red[1][0][cc] + red[1][1][cc] + red[1][2][cc] + red[1][3][cc];
        atomicAdd(&stats[64 + cc], s);
    }
}

// ---------------------------------------------------------------------------
// K5: out = lrelu(s*hsel + t) — pure float4 streaming; finalize folded in.
// ---------------------------------------------------------------------------
__global__ void out_kernel(const float* __restrict__ hsel,
                           const float* __restrict__ stats,
                           const float* __restrict__ gamma,
                           const float* __restrict__ beta,
                           float* __restrict__ out) {
    __shared__ float sS[64], sT[64];
    int tid = threadIdx.x;
    if (tid < 64) {
        const float N = (float)NEDGE;
        float mean = stats[tid] / N;
        float var = stats[64 + tid] / N - mean * mean;
        float s = gamma[tid] * rsqrtf(var + EPSV);
        sS[tid] = s;
        sT[tid] = beta[tid] - mean * s;
    }
    __syncthreads();
    int gid = blockIdx.x * 256 + tid;
#pragma unroll
    for (int r = 0; r < 2; ++r) {
        size_t i4 = (size_t)gid + (size_t)r * 262144;
        size_t i = i4 * 4;
        int c0 = (int)(i & 63);
        float4 h4 = *(const float4*)&hsel[i];
        float4 s4 = *(const float4*)&sS[c0];
        float4 t4 = *(const float4*)&sT[c0];
        float4 o4;
        float hn;
        hn = fmaf(s4.x, h4.x, t4.x); o4.x = (hn >= 0.f) ? hn : SLOPE * hn;
        hn = fmaf(s4.y, h4.y, t4.y); o4.y = (hn >= 0.f) ? hn : SLOPE * hn;
        hn = fmaf(s4.z, h4.z, t4.z); o4.z = (hn >= 0.f) ? hn : SLOPE * hn;
        hn = fmaf(s4.w, h4.w, t4.w); o4.w = (hn >= 0.f) ? hn : SLOPE * hn;
        *(float4*)&out[i] = o4;
    }
}

// ---------------------------------------------------------------------------
extern "C" void kernel_launch(void* const* d_in, const int* in_sizes, int n_in,
                              void* d_out, int out_size, void* d_ws, size_t ws_size,
                              hipStream_t stream) {
    const float* x     = (const float*)d_in[0];
    const float* W     = (const float*)d_in[2];
    const float* bias  = (const float*)d_in[3];
    const float* gamma = (const float*)d_in[4];
    const float* beta  = (const float*)d_in[5];
    float* out = (float*)d_out;

    float* wsf    = (float*)d_ws;
    float* U      = wsf;
    float* V      = wsf + 2097152;
    uint4* xfh    = (uint4*)wsf;                   // aliases U/V, dead after knn
    uint4* xfm    = (uint4*)(wsf + 1048576);
    uint4* xfl    = (uint4*)(wsf + 2097152);
    float* sq     = wsf + 4194304;
    float* stats  = wsf + 4227072;
    int*   idx    = (int*)(wsf + 4227328);
    float* pv     = wsf + 4751616;
    int*   pi     = (int*)(wsf + 5800192);
    float* hsel   = wsf + 4751616;                 // aliases pv+pi (dead after merge)

    hipLaunchKernelGGL(prep_frag, dim3(NPTS / 32), dim3(256), 0, stream, x, xfh, xfm, xfl, sq);
    hipLaunchKernelGGL(knn_kernel, dim3(BATCH * (P / 64) * NQ), dim3(256), 0, stream,
                       (const uint4*)xfh, (const uint4*)xfm, (const uint4*)xfl, sq, pv, pi);
    hipLaunchKernelGGL(merge_kernel, dim3(NPTS / 128), dim3(256), 0, stream, pv, pi, idx);
    hipLaunchKernelGGL(prep_UV, dim3(NPTS / 4), dim3(256), 0, stream, x, W, U, V);
    hipMemsetAsync(stats, 0, 128 * sizeof(float), stream);
    hipLaunchKernelGGL(stats_kernel, dim3(NPTS / 32), dim3(256), 0, stream,
                       U, V, bias, gamma, idx, stats, hsel);
    hipLaunchKernelGGL(out_kernel, dim3(1024), dim3(256), 0, stream,
                       hsel, stats, gamma, beta, out);
}